// Round 4
// baseline (358.484 us; speedup 1.0000x reference)
//
#include <hip/hip_runtime.h>
#include <hip/hip_bf16.h>

#define B_ 2
#define S_ 1536
#define D_ 1024
#define H_ 16
#define DK_ 64

#define RET_ELEMS 3145728      // f32 elems: [B,S,D]
// scores f32[B,H,S,S] follows at out + RET_ELEMS

typedef __attribute__((ext_vector_type(8))) short short8;
typedef __attribute__((ext_vector_type(4))) unsigned short ushort4v;
typedef __attribute__((ext_vector_type(4))) float f32x4;

__device__ __forceinline__ unsigned short bf16_rne(float f) {
    unsigned int u = __builtin_bit_cast(unsigned int, f);
    unsigned int r = (u + 0x7FFFu + ((u >> 16) & 1u)) >> 16;
    return (unsigned short)r;
}

// ---------------- zero colsum ----------------
__global__ void zero_colsum_kernel(float* __restrict__ colsum) {
    const int i = blockIdx.x * 256 + threadIdx.x;
    if (i < B_ * S_) colsum[i] = 0.f;
}

// ---------------- column count of mask1 (sum over q axis) ----------------
__global__ void colcount_kernel(const float* __restrict__ mask1, float* __restrict__ colsum) {
    const int b   = blockIdx.x;
    const int col = blockIdx.y * 256 + threadIdx.x;
    const int q0  = blockIdx.z * (S_ / 8);
    const float* p = mask1 + ((size_t)b * S_ + q0) * S_ + col;
    float s = 0.f;
    #pragma unroll 8
    for (int q = 0; q < S_ / 8; ++q) s += p[(size_t)q * S_];
    atomicAdd(&colsum[b * S_ + col], s);   // integer-valued: exact, order-independent
}

// ---------------- GEMM: C[M,N] = A[M,K] * Bw[N,K]^T + bias ----------------
// A_IS_BF16: A is bf16 (else f32, converted on stage). OUT_F32: C is f32 (else bf16).
template<int A_IS_BF16, int OUT_F32>
__global__ __launch_bounds__(256) void gemm_bt_kernel(
    const void* __restrict__ Av, const float* __restrict__ Bw,
    const float* __restrict__ bias, void* __restrict__ Cv,
    int M, int N, int K)
{
    __shared__ unsigned short As[128][40];
    __shared__ unsigned short Bs[128][40];
    const int tid = threadIdx.x;
    const int w = tid >> 6, lane = tid & 63;
    const int g = lane >> 4, c = lane & 15;
    const int wm = w >> 1, wn = w & 1;
    const int m0 = blockIdx.y * 128, n0 = blockIdx.x * 128;
    const int trow = tid >> 3;          // 0..31
    const int tcol = (tid & 7) * 4;     // 0..28

    f32x4 acc[4][4];
    #pragma unroll
    for (int i = 0; i < 4; ++i)
        #pragma unroll
        for (int j = 0; j < 4; ++j)
            acc[i][j] = f32x4{0.f, 0.f, 0.f, 0.f};

    for (int k0 = 0; k0 < K; k0 += 32) {
        #pragma unroll
        for (int p = 0; p < 4; ++p) {
            const int r = trow + p * 32;
            ushort4v v;
            if (A_IS_BF16) {
                v = *(const ushort4v*)((const unsigned short*)Av + (size_t)(m0 + r) * K + k0 + tcol);
            } else {
                const float* Af = (const float*)Av;
                float4 f = *(const float4*)(Af + (size_t)(m0 + r) * K + k0 + tcol);
                v[0] = bf16_rne(f.x); v[1] = bf16_rne(f.y); v[2] = bf16_rne(f.z); v[3] = bf16_rne(f.w);
            }
            *(ushort4v*)&As[r][tcol] = v;
            float4 f = *(const float4*)(Bw + (size_t)(n0 + r) * K + k0 + tcol);
            ushort4v bvv;
            bvv[0] = bf16_rne(f.x); bvv[1] = bf16_rne(f.y); bvv[2] = bf16_rne(f.z); bvv[3] = bf16_rne(f.w);
            *(ushort4v*)&Bs[r][tcol] = bvv;
        }
        __syncthreads();
        short8 a[4], bfr[4];
        #pragma unroll
        for (int m = 0; m < 4; ++m) a[m]   = *(const short8*)&As[wm * 64 + m * 16 + c][g * 8];
        #pragma unroll
        for (int n = 0; n < 4; ++n) bfr[n] = *(const short8*)&Bs[wn * 64 + n * 16 + c][g * 8];
        #pragma unroll
        for (int m = 0; m < 4; ++m)
            #pragma unroll
            for (int n = 0; n < 4; ++n)
                acc[m][n] = __builtin_amdgcn_mfma_f32_16x16x32_bf16(a[m], bfr[n], acc[m][n], 0, 0, 0);
        __syncthreads();
    }
    #pragma unroll
    for (int n = 0; n < 4; ++n) {
        const int col = n0 + wn * 64 + n * 16 + c;
        const float bval = bias[col];
        #pragma unroll
        for (int m = 0; m < 4; ++m) {
            const int row0 = m0 + wm * 64 + m * 16 + g * 4;
            #pragma unroll
            for (int r = 0; r < 4; ++r) {
                if (OUT_F32) ((float*)Cv)[(size_t)(row0 + r) * N + col] = acc[m][n][r] + bval;
                else ((unsigned short*)Cv)[(size_t)(row0 + r) * N + col] = bf16_rne(acc[m][n][r] + bval);
            }
        }
    }
}

// ---------------- fused attention: f32 scores inline + online softmax + PV -> bf16 X ----------------
__global__ __launch_bounds__(256) void attn_kernel(
    const unsigned short* __restrict__ Qb, const unsigned short* __restrict__ Kb,
    const unsigned short* __restrict__ Vb, const int* __restrict__ mask,
    const float* __restrict__ mask1, const float* __restrict__ colsum,
    float* __restrict__ scores, unsigned short* __restrict__ X)
{
    const int qt = blockIdx.x;
    const int h  = blockIdx.y;
    const int b  = blockIdx.z;
    const int tid = threadIdx.x;
    const int w = tid >> 6, lane = tid & 63;
    const int g = lane >> 4, c = lane & 15;

    __shared__ unsigned short VT_lds[64][72];   // [dk][k] transposed V tile
    __shared__ unsigned short P_lds[4][16][72];

    const int qrow0 = qt * 64 + w * 16;
    const unsigned short* qptr = Qb + ((size_t)b * S_ + qrow0 + c) * D_ + h * DK_;
    const short8 qf0 = *(const short8*)(qptr + g * 8);
    const short8 qf1 = *(const short8*)(qptr + 32 + g * 8);

    float mrow[4], lrow[4];
    f32x4 o[4];
    #pragma unroll
    for (int r = 0; r < 4; ++r) { mrow[r] = -INFINITY; lrow[r] = 0.f; }
    #pragma unroll
    for (int n = 0; n < 4; ++n) o[n] = f32x4{0.f, 0.f, 0.f, 0.f};

    const size_t score_base = (((size_t)(b * H_ + h)) * S_ + qrow0) * S_;
    const int kr = tid & 63, half = tid >> 6;

    for (int kt = 0; kt < S_ / 64; ++kt) {
        const int k0 = kt * 64;
        __syncthreads();   // previous PV done -> VT_lds reusable
        {
            const unsigned short* vsrc = Vb + ((size_t)b * S_ + k0 + kr) * D_ + h * DK_ + half * 16;
            short8 v0 = *(const short8*)vsrc;
            short8 v1 = *(const short8*)(vsrc + 8);
            #pragma unroll
            for (int j = 0; j < 8; ++j) {
                VT_lds[half * 16 + j][kr]     = (unsigned short)v0[j];
                VT_lds[half * 16 + 8 + j][kr] = (unsigned short)v1[j];
            }
        }
        __syncthreads();   // VT_lds ready

        // ---- S = Q K^T ----
        f32x4 sacc[4];
        #pragma unroll
        for (int n = 0; n < 4; ++n) sacc[n] = f32x4{0.f, 0.f, 0.f, 0.f};
        #pragma unroll
        for (int n = 0; n < 4; ++n) {
            const unsigned short* kp = Kb + ((size_t)b * S_ + k0 + n * 16 + c) * D_ + h * DK_;
            short8 kf0 = *(const short8*)(kp + g * 8);
            short8 kf1 = *(const short8*)(kp + 32 + g * 8);
            sacc[n] = __builtin_amdgcn_mfma_f32_16x16x32_bf16(qf0, kf0, sacc[n], 0, 0, 0);
            sacc[n] = __builtin_amdgcn_mfma_f32_16x16x32_bf16(qf1, kf1, sacc[n], 0, 0, 0);
        }
        // ---- scale/factor/mask, write f32 scores, track tile max ----
        float sv[4][4];
        float tmax[4] = {-INFINITY, -INFINITY, -INFINITY, -INFINITY};
        #pragma unroll
        for (int n = 0; n < 4; ++n) {
            const int key = k0 + n * 16 + c;
            const int km = mask[b * S_ + key];
            const float cnt = colsum[b * S_ + key];
            const float icnt = (cnt > 0.f) ? (1.f / cnt) : 0.f;
            #pragma unroll
            for (int r = 0; r < 4; ++r) {
                const int q = qrow0 + g * 4 + r;
                const float m1v = mask1[((size_t)b * S_ + q) * S_ + key];
                float s = sacc[n][r] * 0.125f * (1.f + m1v * icnt);
                s = (km == 0) ? -1e9f : s;
                sv[n][r] = s;
                scores[score_base + (size_t)(g * 4 + r) * S_ + key] = s;
                tmax[r] = fmaxf(tmax[r], s);
            }
        }
        // ---- online softmax update ----
        #pragma unroll
        for (int r = 0; r < 4; ++r) {
            float t = tmax[r];
            t = fmaxf(t, __shfl_xor(t, 1));
            t = fmaxf(t, __shfl_xor(t, 2));
            t = fmaxf(t, __shfl_xor(t, 4));
            t = fmaxf(t, __shfl_xor(t, 8));
            const float nm = fmaxf(mrow[r], t);
            const float sc = __expf(mrow[r] - nm);   // exp(-inf)=0 first tile
            mrow[r] = nm;
            lrow[r] *= sc;
            #pragma unroll
            for (int n = 0; n < 4; ++n) o[n][r] *= sc;
        }
        #pragma unroll
        for (int n = 0; n < 4; ++n)
            #pragma unroll
            for (int r = 0; r < 4; ++r) {
                const float p = __expf(sv[n][r] - mrow[r]);
                lrow[r] += p;
                P_lds[w][g * 4 + r][n * 16 + c] = bf16_rne(p);
            }
        __syncthreads();

        // ---- O += P V ----
        #pragma unroll
        for (int kk = 0; kk < 2; ++kk) {
            const short8 pa = *(const short8*)&P_lds[w][c][kk * 32 + g * 8];
            #pragma unroll
            for (int n = 0; n < 4; ++n) {
                const short8 vf = *(const short8*)&VT_lds[n * 16 + c][kk * 32 + g * 8];
                o[n] = __builtin_amdgcn_mfma_f32_16x16x32_bf16(pa, vf, o[n], 0, 0, 0);
            }
        }
    }
    // ---- finalize ----
    float linv[4];
    #pragma unroll
    for (int r = 0; r < 4; ++r) {
        float t = lrow[r];
        t += __shfl_xor(t, 1);
        t += __shfl_xor(t, 2);
        t += __shfl_xor(t, 4);
        t += __shfl_xor(t, 8);
        linv[r] = 1.f / t;
    }
    #pragma unroll
    for (int n = 0; n < 4; ++n)
        #pragma unroll
        for (int r = 0; r < 4; ++r) {
            const size_t idx = ((size_t)b * S_ + qrow0 + g * 4 + r) * D_ + h * DK_ + n * 16 + c;
            X[idx] = bf16_rne(o[n][r] * linv[r]);
        }
}

extern "C" void kernel_launch(void* const* d_in, const int* in_sizes, int n_in,
                              void* d_out, int out_size, void* d_ws, size_t ws_size,
                              hipStream_t stream) {
    const float* query = (const float*)d_in[0];
    const float* key   = (const float*)d_in[1];
    const float* value = (const float*)d_in[2];
    const int*   mask  = (const int*)d_in[3];
    const float* mask1 = (const float*)d_in[4];
    const float* Wq = (const float*)d_in[5];
    const float* bq = (const float*)d_in[6];
    const float* Wk = (const float*)d_in[7];
    const float* bk = (const float*)d_in[8];
    const float* Wv = (const float*)d_in[9];
    const float* bv = (const float*)d_in[10];
    const float* Wo = (const float*)d_in[11];
    const float* bo = (const float*)d_in[12];

    float* ret_out    = (float*)d_out;               // f32 [B,S,D]
    float* scores_out = ret_out + RET_ELEMS;         // f32 [B,H,S,S]

    const size_t SZ = (size_t)B_ * S_ * D_;          // 3,145,728 elems
    // ws layout (~25.2 MB): colsum(16KB) | Qb | Kb | Vb | Xb (bf16)
    float* colsum = (float*)d_ws;
    unsigned short* Qb = (unsigned short*)((char*)d_ws + 16384);
    unsigned short* Kb = Qb + SZ;
    unsigned short* Vb = Kb + SZ;
    unsigned short* Xb = Vb + SZ;

    zero_colsum_kernel<<<12, 256, 0, stream>>>(colsum);
    colcount_kernel<<<dim3(B_, S_ / 256, 8), 256, 0, stream>>>(mask1, colsum);

    const dim3 gg(D_ / 128, (B_ * S_) / 128);  // (8, 24)
    gemm_bt_kernel<0, 0><<<gg, 256, 0, stream>>>(query, Wq, bq, Qb, B_ * S_, D_, D_);
    gemm_bt_kernel<0, 0><<<gg, 256, 0, stream>>>(key,   Wk, bk, Kb, B_ * S_, D_, D_);
    gemm_bt_kernel<0, 0><<<gg, 256, 0, stream>>>(value, Wv, bv, Vb, B_ * S_, D_, D_);

    attn_kernel<<<dim3(S_ / 64, H_, B_), 256, 0, stream>>>(Qb, Kb, Vb, mask, mask1, colsum, scores_out, Xb);

    gemm_bt_kernel<1, 1><<<gg, 256, 0, stream>>>(Xb, Wo, bo, ret_out, B_ * S_, D_, D_);
}

// Round 5
// 268.964 us; speedup vs baseline: 1.3328x; 1.3328x over previous
//
#include <hip/hip_runtime.h>
#include <hip/hip_bf16.h>

#define B_ 2
#define S_ 1536
#define D_ 1024
#define H_ 16
#define DK_ 64
#define KW_ 48                 // S_/32 mask-bit words per row

#define RET_ELEMS 3145728      // f32 elems: [B,S,D]

typedef __attribute__((ext_vector_type(8))) short short8;
typedef __attribute__((ext_vector_type(8))) unsigned short ushort8v;
typedef __attribute__((ext_vector_type(4))) unsigned short ushort4v;
typedef __attribute__((ext_vector_type(4))) float f32x4;

__device__ __forceinline__ unsigned short bf16_rne(float f) {
    unsigned int u = __builtin_bit_cast(unsigned int, f);
    unsigned int r = (u + 0x7FFFu + ((u >> 16) & 1u)) >> 16;
    return (unsigned short)r;
}

// ---------------- zero colsum ----------------
__global__ void zero_colsum_kernel(float* __restrict__ colsum) {
    const int i = blockIdx.x * 256 + threadIdx.x;
    if (i < B_ * S_) colsum[i] = 0.f;
}

// ---------------- column count of mask1 (sum over q axis) ----------------
__global__ void colcount_kernel(const float* __restrict__ mask1, float* __restrict__ colsum) {
    const int b   = blockIdx.x;
    const int col = blockIdx.y * 256 + threadIdx.x;
    const int q0  = blockIdx.z * (S_ / 8);
    const float* p = mask1 + ((size_t)b * S_ + q0) * S_ + col;
    float s = 0.f;
    #pragma unroll 8
    for (int q = 0; q < S_ / 8; ++q) s += p[(size_t)q * S_];
    atomicAdd(&colsum[b * S_ + col], s);   // integer-valued: exact, order-independent
}

// ---------------- pack mask1 into bits: word[(b*S+q)*48 + k/32] ----------------
__global__ void bitpack_kernel(const float* __restrict__ mask1, unsigned int* __restrict__ bits) {
    const size_t gid = (size_t)blockIdx.x * 256 + threadIdx.x;   // over B*S*S
    const float v = mask1[gid];
    const unsigned long long bal = __ballot(v != 0.f);
    const int l = threadIdx.x & 63;
    if (l == 0)       bits[gid >> 5] = (unsigned int)bal;
    else if (l == 32) bits[gid >> 5] = (unsigned int)(bal >> 32);
}

// ---------------- fused QKV projection GEMM: 128x128 tile, BK=64, 512 threads ----------------
struct Proj { const float* A; const float* W; const float* bias; unsigned short* C; };

__global__ __launch_bounds__(512) void qkv_gemm_kernel(Proj p0, Proj p1, Proj p2) {
    const int z = blockIdx.z;
    const float* A    = z == 0 ? p0.A    : (z == 1 ? p1.A    : p2.A);
    const float* W    = z == 0 ? p0.W    : (z == 1 ? p1.W    : p2.W);
    const float* bias = z == 0 ? p0.bias : (z == 1 ? p1.bias : p2.bias);
    unsigned short* C = z == 0 ? p0.C    : (z == 1 ? p1.C    : p2.C);

    __shared__ unsigned short As[128][72];
    __shared__ unsigned short Bs[128][72];
    const int tid = threadIdx.x;
    const int w = tid >> 6, lane = tid & 63;
    const int g = lane >> 4, c = lane & 15;
    const int wm = w >> 2, wn = w & 3;        // 2x4 waves, wave tile 64x32
    const int m0 = blockIdx.y * 128, n0 = blockIdx.x * 128;
    const int trow = tid >> 2;                // 0..127
    const int tcol = (tid & 3) * 16;          // 0,16,32,48

    f32x4 acc[4][2];
    #pragma unroll
    for (int m = 0; m < 4; ++m)
        #pragma unroll
        for (int n = 0; n < 2; ++n)
            acc[m][n] = f32x4{0.f, 0.f, 0.f, 0.f};

    for (int k0 = 0; k0 < D_; k0 += 64) {
        {
            const float* ap = A + (size_t)(m0 + trow) * D_ + k0 + tcol;
            float4 f0 = *(const float4*)(ap);
            float4 f1 = *(const float4*)(ap + 4);
            float4 f2 = *(const float4*)(ap + 8);
            float4 f3 = *(const float4*)(ap + 12);
            ushort8v u0, u1;
            u0[0]=bf16_rne(f0.x); u0[1]=bf16_rne(f0.y); u0[2]=bf16_rne(f0.z); u0[3]=bf16_rne(f0.w);
            u0[4]=bf16_rne(f1.x); u0[5]=bf16_rne(f1.y); u0[6]=bf16_rne(f1.z); u0[7]=bf16_rne(f1.w);
            u1[0]=bf16_rne(f2.x); u1[1]=bf16_rne(f2.y); u1[2]=bf16_rne(f2.z); u1[3]=bf16_rne(f2.w);
            u1[4]=bf16_rne(f3.x); u1[5]=bf16_rne(f3.y); u1[6]=bf16_rne(f3.z); u1[7]=bf16_rne(f3.w);
            *(ushort8v*)&As[trow][tcol]     = u0;
            *(ushort8v*)&As[trow][tcol + 8] = u1;
            const float* wp = W + (size_t)(n0 + trow) * D_ + k0 + tcol;
            f0 = *(const float4*)(wp);
            f1 = *(const float4*)(wp + 4);
            f2 = *(const float4*)(wp + 8);
            f3 = *(const float4*)(wp + 12);
            u0[0]=bf16_rne(f0.x); u0[1]=bf16_rne(f0.y); u0[2]=bf16_rne(f0.z); u0[3]=bf16_rne(f0.w);
            u0[4]=bf16_rne(f1.x); u0[5]=bf16_rne(f1.y); u0[6]=bf16_rne(f1.z); u0[7]=bf16_rne(f1.w);
            u1[0]=bf16_rne(f2.x); u1[1]=bf16_rne(f2.y); u1[2]=bf16_rne(f2.z); u1[3]=bf16_rne(f2.w);
            u1[4]=bf16_rne(f3.x); u1[5]=bf16_rne(f3.y); u1[6]=bf16_rne(f3.z); u1[7]=bf16_rne(f3.w);
            *(ushort8v*)&Bs[trow][tcol]     = u0;
            *(ushort8v*)&Bs[trow][tcol + 8] = u1;
        }
        __syncthreads();
        #pragma unroll
        for (int kk = 0; kk < 2; ++kk) {
            short8 a[4], bb[2];
            #pragma unroll
            for (int m = 0; m < 4; ++m) a[m]  = *(const short8*)&As[wm * 64 + m * 16 + c][kk * 32 + g * 8];
            #pragma unroll
            for (int n = 0; n < 2; ++n) bb[n] = *(const short8*)&Bs[wn * 32 + n * 16 + c][kk * 32 + g * 8];
            #pragma unroll
            for (int m = 0; m < 4; ++m)
                #pragma unroll
                for (int n = 0; n < 2; ++n)
                    acc[m][n] = __builtin_amdgcn_mfma_f32_16x16x32_bf16(a[m], bb[n], acc[m][n], 0, 0, 0);
        }
        __syncthreads();
    }
    #pragma unroll
    for (int n = 0; n < 2; ++n) {
        const int col = n0 + wn * 32 + n * 16 + c;
        const float bval = bias[col];
        #pragma unroll
        for (int m = 0; m < 4; ++m) {
            const int row0 = m0 + wm * 64 + m * 16 + g * 4;
            #pragma unroll
            for (int r = 0; r < 4; ++r)
                C[(size_t)(row0 + r) * D_ + col] = bf16_rne(acc[m][n][r] + bval);
        }
    }
}

// ---------------- final projection: 64x64 tile, 256 threads, bf16 A, f32 out ----------------
__global__ __launch_bounds__(256) void out_gemm_kernel(
    const unsigned short* __restrict__ A, const float* __restrict__ W,
    const float* __restrict__ bias, float* __restrict__ C)
{
    __shared__ unsigned short As[64][72];
    __shared__ unsigned short Bs[64][72];
    const int tid = threadIdx.x;
    const int w = tid >> 6, lane = tid & 63;
    const int g = lane >> 4, c = lane & 15;
    const int wm = w >> 1, wn = w & 1;        // 2x2 waves, wave tile 32x32
    const int m0 = blockIdx.y * 64, n0 = blockIdx.x * 64;
    const int trow = tid >> 2;                // 0..63
    const int tcol = (tid & 3) * 16;

    f32x4 acc[2][2];
    #pragma unroll
    for (int m = 0; m < 2; ++m)
        #pragma unroll
        for (int n = 0; n < 2; ++n)
            acc[m][n] = f32x4{0.f, 0.f, 0.f, 0.f};

    for (int k0 = 0; k0 < D_; k0 += 64) {
        {
            const unsigned short* ap = A + (size_t)(m0 + trow) * D_ + k0 + tcol;
            *(ushort8v*)&As[trow][tcol]     = *(const ushort8v*)ap;
            *(ushort8v*)&As[trow][tcol + 8] = *(const ushort8v*)(ap + 8);
            const float* wp = W + (size_t)(n0 + trow) * D_ + k0 + tcol;
            float4 f0 = *(const float4*)(wp);
            float4 f1 = *(const float4*)(wp + 4);
            float4 f2 = *(const float4*)(wp + 8);
            float4 f3 = *(const float4*)(wp + 12);
            ushort8v u0, u1;
            u0[0]=bf16_rne(f0.x); u0[1]=bf16_rne(f0.y); u0[2]=bf16_rne(f0.z); u0[3]=bf16_rne(f0.w);
            u0[4]=bf16_rne(f1.x); u0[5]=bf16_rne(f1.y); u0[6]=bf16_rne(f1.z); u0[7]=bf16_rne(f1.w);
            u1[0]=bf16_rne(f2.x); u1[1]=bf16_rne(f2.y); u1[2]=bf16_rne(f2.z); u1[3]=bf16_rne(f2.w);
            u1[4]=bf16_rne(f3.x); u1[5]=bf16_rne(f3.y); u1[6]=bf16_rne(f3.z); u1[7]=bf16_rne(f3.w);
            *(ushort8v*)&Bs[trow][tcol]     = u0;
            *(ushort8v*)&Bs[trow][tcol + 8] = u1;
        }
        __syncthreads();
        #pragma unroll
        for (int kk = 0; kk < 2; ++kk) {
            short8 a[2], bb[2];
            #pragma unroll
            for (int m = 0; m < 2; ++m) a[m]  = *(const short8*)&As[wm * 32 + m * 16 + c][kk * 32 + g * 8];
            #pragma unroll
            for (int n = 0; n < 2; ++n) bb[n] = *(const short8*)&Bs[wn * 32 + n * 16 + c][kk * 32 + g * 8];
            #pragma unroll
            for (int m = 0; m < 2; ++m)
                #pragma unroll
                for (int n = 0; n < 2; ++n)
                    acc[m][n] = __builtin_amdgcn_mfma_f32_16x16x32_bf16(a[m], bb[n], acc[m][n], 0, 0, 0);
        }
        __syncthreads();
    }
    #pragma unroll
    for (int n = 0; n < 2; ++n) {
        const int col = n0 + wn * 32 + n * 16 + c;
        const float bval = bias[col];
        #pragma unroll
        for (int m = 0; m < 2; ++m) {
            const int row0 = m0 + wm * 32 + m * 16 + g * 4;
            #pragma unroll
            for (int r = 0; r < 4; ++r)
                C[(size_t)(row0 + r) * D_ + col] = acc[m][n][r] + bval;
        }
    }
}

// ---------------- fused attention: f32 scores inline + online softmax + PV -> bf16 X ----------------
__global__ __launch_bounds__(256) void attn_kernel(
    const unsigned short* __restrict__ Qb, const unsigned short* __restrict__ Kb,
    const unsigned short* __restrict__ Vb, const int* __restrict__ mask,
    const unsigned int* __restrict__ bits, const float* __restrict__ colsum,
    float* __restrict__ scores, unsigned short* __restrict__ X)
{
    const int qt = blockIdx.x;
    const int h  = blockIdx.y;
    const int b  = blockIdx.z;
    const int tid = threadIdx.x;
    const int w = tid >> 6, lane = tid & 63;
    const int g = lane >> 4, c = lane & 15;

    __shared__ unsigned short VT_lds[64][72];   // [dk][k] transposed V tile
    __shared__ unsigned short P_lds[4][16][72];

    const int qrow0 = qt * 64 + w * 16;
    const unsigned short* qptr = Qb + ((size_t)b * S_ + qrow0 + c) * D_ + h * DK_;
    const short8 qf0 = *(const short8*)(qptr + g * 8);
    const short8 qf1 = *(const short8*)(qptr + 32 + g * 8);

    float mrow[4], lrow[4];
    f32x4 o[4];
    #pragma unroll
    for (int r = 0; r < 4; ++r) { mrow[r] = -INFINITY; lrow[r] = 0.f; }
    #pragma unroll
    for (int n = 0; n < 4; ++n) o[n] = f32x4{0.f, 0.f, 0.f, 0.f};

    const size_t score_base = (((size_t)(b * H_ + h)) * S_ + qrow0) * S_;
    const unsigned int* bits_row = bits + ((size_t)b * S_ + qrow0) * KW_;
    const int kr = tid & 63, half = tid >> 6;

    for (int kt = 0; kt < S_ / 64; ++kt) {
        const int k0 = kt * 64;
        __syncthreads();   // previous PV done -> VT_lds reusable
        {
            const unsigned short* vsrc = Vb + ((size_t)b * S_ + k0 + kr) * D_ + h * DK_ + half * 16;
            short8 v0 = *(const short8*)vsrc;
            short8 v1 = *(const short8*)(vsrc + 8);
            #pragma unroll
            for (int j = 0; j < 8; ++j) {
                VT_lds[half * 16 + j][kr]     = (unsigned short)v0[j];
                VT_lds[half * 16 + 8 + j][kr] = (unsigned short)v1[j];
            }
        }
        __syncthreads();   // VT_lds ready

        // ---- S = Q K^T ----
        f32x4 sacc[4];
        #pragma unroll
        for (int n = 0; n < 4; ++n) sacc[n] = f32x4{0.f, 0.f, 0.f, 0.f};
        #pragma unroll
        for (int n = 0; n < 4; ++n) {
            const unsigned short* kp = Kb + ((size_t)b * S_ + k0 + n * 16 + c) * D_ + h * DK_;
            short8 kf0 = *(const short8*)(kp + g * 8);
            short8 kf1 = *(const short8*)(kp + 32 + g * 8);
            sacc[n] = __builtin_amdgcn_mfma_f32_16x16x32_bf16(qf0, kf0, sacc[n], 0, 0, 0);
            sacc[n] = __builtin_amdgcn_mfma_f32_16x16x32_bf16(qf1, kf1, sacc[n], 0, 0, 0);
        }
        // ---- mask1 bits for this tile: 2 words per q-row ----
        const int kw = k0 >> 5;
        unsigned int wb[4][2];
        #pragma unroll
        for (int r = 0; r < 4; ++r) {
            const unsigned int* bp = bits_row + (size_t)(g * 4 + r) * KW_ + kw;
            wb[r][0] = bp[0]; wb[r][1] = bp[1];
        }
        // ---- scale/factor/mask, write f32 scores, track tile max ----
        float sv[4][4];
        float tmax[4] = {-INFINITY, -INFINITY, -INFINITY, -INFINITY};
        #pragma unroll
        for (int n = 0; n < 4; ++n) {
            const int key = k0 + n * 16 + c;
            const int km = mask[b * S_ + key];
            const float cnt = colsum[b * S_ + key];
            const float icnt = (cnt > 0.f) ? (1.f / cnt) : 0.f;
            #pragma unroll
            for (int r = 0; r < 4; ++r) {
                const float fac = 1.f + ((((wb[r][n >> 1] >> (((n & 1) << 4) + c)) & 1u)) ? icnt : 0.f);
                float s = sacc[n][r] * 0.125f * fac;
                s = (km == 0) ? -1e9f : s;
                sv[n][r] = s;
                scores[score_base + (size_t)(g * 4 + r) * S_ + key] = s;
                tmax[r] = fmaxf(tmax[r], s);
            }
        }
        // ---- online softmax update ----
        #pragma unroll
        for (int r = 0; r < 4; ++r) {
            float t = tmax[r];
            t = fmaxf(t, __shfl_xor(t, 1));
            t = fmaxf(t, __shfl_xor(t, 2));
            t = fmaxf(t, __shfl_xor(t, 4));
            t = fmaxf(t, __shfl_xor(t, 8));
            const float nm = fmaxf(mrow[r], t);
            const float sc = __expf(mrow[r] - nm);   // exp(-inf)=0 first tile
            mrow[r] = nm;
            lrow[r] *= sc;
            #pragma unroll
            for (int n = 0; n < 4; ++n) o[n][r] *= sc;
        }
        #pragma unroll
        for (int n = 0; n < 4; ++n)
            #pragma unroll
            for (int r = 0; r < 4; ++r) {
                const float p = __expf(sv[n][r] - mrow[r]);
                lrow[r] += p;
                P_lds[w][g * 4 + r][n * 16 + c] = bf16_rne(p);
            }
        __syncthreads();

        // ---- O += P V ----
        #pragma unroll
        for (int kk = 0; kk < 2; ++kk) {
            const short8 pa = *(const short8*)&P_lds[w][c][kk * 32 + g * 8];
            #pragma unroll
            for (int n = 0; n < 4; ++n) {
                const short8 vf = *(const short8*)&VT_lds[n * 16 + c][kk * 32 + g * 8];
                o[n] = __builtin_amdgcn_mfma_f32_16x16x32_bf16(pa, vf, o[n], 0, 0, 0);
            }
        }
    }
    // ---- finalize ----
    float linv[4];
    #pragma unroll
    for (int r = 0; r < 4; ++r) {
        float t = lrow[r];
        t += __shfl_xor(t, 1);
        t += __shfl_xor(t, 2);
        t += __shfl_xor(t, 4);
        t += __shfl_xor(t, 8);
        linv[r] = 1.f / t;
    }
    #pragma unroll
    for (int n = 0; n < 4; ++n)
        #pragma unroll
        for (int r = 0; r < 4; ++r) {
            const size_t idx = ((size_t)b * S_ + qrow0 + g * 4 + r) * D_ + h * DK_ + n * 16 + c;
            X[idx] = bf16_rne(o[n][r] * linv[r]);
        }
}

extern "C" void kernel_launch(void* const* d_in, const int* in_sizes, int n_in,
                              void* d_out, int out_size, void* d_ws, size_t ws_size,
                              hipStream_t stream) {
    const float* query = (const float*)d_in[0];
    const float* key   = (const float*)d_in[1];
    const float* value = (const float*)d_in[2];
    const int*   mask  = (const int*)d_in[3];
    const float* mask1 = (const float*)d_in[4];
    const float* Wq = (const float*)d_in[5];
    const float* bq = (const float*)d_in[6];
    const float* Wk = (const float*)d_in[7];
    const float* bk = (const float*)d_in[8];
    const float* Wv = (const float*)d_in[9];
    const float* bv = (const float*)d_in[10];
    const float* Wo = (const float*)d_in[11];
    const float* bo = (const float*)d_in[12];

    float* ret_out    = (float*)d_out;               // f32 [B,S,D]
    float* scores_out = ret_out + RET_ELEMS;         // f32 [B,H,S,S]

    const size_t SZ = (size_t)B_ * S_ * D_;          // 3,145,728 elems
    // ws layout (~24.6 MiB): colsum(16K) | bits(576K) | Qb | Kb | Vb | Xb (bf16)
    float* colsum = (float*)d_ws;
    unsigned int* bits = (unsigned int*)((char*)d_ws + 16384);
    unsigned short* Qb = (unsigned short*)((char*)d_ws + 16384 + 589824);
    unsigned short* Kb = Qb + SZ;
    unsigned short* Vb = Kb + SZ;
    unsigned short* Xb = Vb + SZ;

    zero_colsum_kernel<<<12, 256, 0, stream>>>(colsum);
    colcount_kernel<<<dim3(B_, S_ / 256, 8), 256, 0, stream>>>(mask1, colsum);
    bitpack_kernel<<<(B_ * S_ * S_) / 256, 256, 0, stream>>>(mask1, bits);

    Proj p0{query, Wq, bq, Qb}, p1{key, Wk, bk, Kb}, p2{value, Wv, bv, Vb};
    qkv_gemm_kernel<<<dim3(D_ / 128, (B_ * S_) / 128, 3), 512, 0, stream>>>(p0, p1, p2);

    attn_kernel<<<dim3(S_ / 64, H_, B_), 256, 0, stream>>>(Qb, Kb, Vb, mask, bits, colsum, scores_out, Xb);

    out_gemm_kernel<<<dim3(D_ / 64, (B_ * S_) / 64), 256, 0, stream>>>(Xb, Wo, bo, ret_out);
}

// Round 6
// 242.923 us; speedup vs baseline: 1.4757x; 1.1072x over previous
//
#include <hip/hip_runtime.h>
#include <hip/hip_bf16.h>

#define B_ 2
#define S_ 1536
#define D_ 1024
#define H_ 16
#define DK_ 64
#define KW_ 48                 // S_/32 mask-bit words per row
#define NT_ 24                 // S_/64 key tiles

#define RET_ELEMS 3145728      // f32 elems: [B,S,D]

typedef __attribute__((ext_vector_type(8))) short short8;
typedef __attribute__((ext_vector_type(8))) unsigned short ushort8v;
typedef __attribute__((ext_vector_type(4))) unsigned short ushort4v;
typedef __attribute__((ext_vector_type(4))) float f32x4;

__device__ __forceinline__ unsigned short bf16_rne(float f) {
    unsigned int u = __builtin_bit_cast(unsigned int, f);
    unsigned int r = (u + 0x7FFFu + ((u >> 16) & 1u)) >> 16;
    return (unsigned short)r;
}

// ---------------- zero colsum ----------------
__global__ void zero_colsum_kernel(float* __restrict__ colsum) {
    const int i = blockIdx.x * 256 + threadIdx.x;
    if (i < B_ * S_) colsum[i] = 0.f;
}

// ---------------- column count of mask1 (sum over q axis) ----------------
__global__ void colcount_kernel(const float* __restrict__ mask1, float* __restrict__ colsum) {
    const int b   = blockIdx.x;
    const int col = blockIdx.y * 256 + threadIdx.x;
    const int q0  = blockIdx.z * (S_ / 8);
    const float* p = mask1 + ((size_t)b * S_ + q0) * S_ + col;
    float s = 0.f;
    #pragma unroll 8
    for (int q = 0; q < S_ / 8; ++q) s += p[(size_t)q * S_];
    atomicAdd(&colsum[b * S_ + col], s);   // integer-valued: exact, order-independent
}

// ---------------- pack mask1 into bits: word[(b*S+q)*48 + k/32] ----------------
__global__ void bitpack_kernel(const float* __restrict__ mask1, unsigned int* __restrict__ bits) {
    const size_t gid = (size_t)blockIdx.x * 256 + threadIdx.x;   // over B*S*S
    const float v = mask1[gid];
    const unsigned long long bal = __ballot(v != 0.f);
    const int l = threadIdx.x & 63;
    if (l == 0)       bits[gid >> 5] = (unsigned int)bal;
    else if (l == 32) bits[gid >> 5] = (unsigned int)(bal >> 32);
}

// ---------------- fused QKV projection GEMM: 128x128 tile, BK=64, 512 threads ----------------
struct Proj { const float* A; const float* W; const float* bias; unsigned short* C; };

__global__ __launch_bounds__(512) void qkv_gemm_kernel(Proj p0, Proj p1, Proj p2) {
    const int z = blockIdx.z;
    const float* A    = z == 0 ? p0.A    : (z == 1 ? p1.A    : p2.A);
    const float* W    = z == 0 ? p0.W    : (z == 1 ? p1.W    : p2.W);
    const float* bias = z == 0 ? p0.bias : (z == 1 ? p1.bias : p2.bias);
    unsigned short* C = z == 0 ? p0.C    : (z == 1 ? p1.C    : p2.C);

    __shared__ unsigned short As[128][72];
    __shared__ unsigned short Bs[128][72];
    const int tid = threadIdx.x;
    const int w = tid >> 6, lane = tid & 63;
    const int g = lane >> 4, c = lane & 15;
    const int wm = w >> 2, wn = w & 3;        // 2x4 waves, wave tile 64x32
    const int m0 = blockIdx.y * 128, n0 = blockIdx.x * 128;
    const int trow = tid >> 2;                // 0..127
    const int tcol = (tid & 3) * 16;          // 0,16,32,48

    f32x4 acc[4][2];
    #pragma unroll
    for (int m = 0; m < 4; ++m)
        #pragma unroll
        for (int n = 0; n < 2; ++n)
            acc[m][n] = f32x4{0.f, 0.f, 0.f, 0.f};

    for (int k0 = 0; k0 < D_; k0 += 64) {
        {
            const float* ap = A + (size_t)(m0 + trow) * D_ + k0 + tcol;
            float4 f0 = *(const float4*)(ap);
            float4 f1 = *(const float4*)(ap + 4);
            float4 f2 = *(const float4*)(ap + 8);
            float4 f3 = *(const float4*)(ap + 12);
            ushort8v u0, u1;
            u0[0]=bf16_rne(f0.x); u0[1]=bf16_rne(f0.y); u0[2]=bf16_rne(f0.z); u0[3]=bf16_rne(f0.w);
            u0[4]=bf16_rne(f1.x); u0[5]=bf16_rne(f1.y); u0[6]=bf16_rne(f1.z); u0[7]=bf16_rne(f1.w);
            u1[0]=bf16_rne(f2.x); u1[1]=bf16_rne(f2.y); u1[2]=bf16_rne(f2.z); u1[3]=bf16_rne(f2.w);
            u1[4]=bf16_rne(f3.x); u1[5]=bf16_rne(f3.y); u1[6]=bf16_rne(f3.z); u1[7]=bf16_rne(f3.w);
            *(ushort8v*)&As[trow][tcol]     = u0;
            *(ushort8v*)&As[trow][tcol + 8] = u1;
            const float* wp = W + (size_t)(n0 + trow) * D_ + k0 + tcol;
            f0 = *(const float4*)(wp);
            f1 = *(const float4*)(wp + 4);
            f2 = *(const float4*)(wp + 8);
            f3 = *(const float4*)(wp + 12);
            u0[0]=bf16_rne(f0.x); u0[1]=bf16_rne(f0.y); u0[2]=bf16_rne(f0.z); u0[3]=bf16_rne(f0.w);
            u0[4]=bf16_rne(f1.x); u0[5]=bf16_rne(f1.y); u0[6]=bf16_rne(f1.z); u0[7]=bf16_rne(f1.w);
            u1[0]=bf16_rne(f2.x); u1[1]=bf16_rne(f2.y); u1[2]=bf16_rne(f2.z); u1[3]=bf16_rne(f2.w);
            u1[4]=bf16_rne(f3.x); u1[5]=bf16_rne(f3.y); u1[6]=bf16_rne(f3.z); u1[7]=bf16_rne(f3.w);
            *(ushort8v*)&Bs[trow][tcol]     = u0;
            *(ushort8v*)&Bs[trow][tcol + 8] = u1;
        }
        __syncthreads();
        #pragma unroll
        for (int kk = 0; kk < 2; ++kk) {
            short8 a[4], bb[2];
            #pragma unroll
            for (int m = 0; m < 4; ++m) a[m]  = *(const short8*)&As[wm * 64 + m * 16 + c][kk * 32 + g * 8];
            #pragma unroll
            for (int n = 0; n < 2; ++n) bb[n] = *(const short8*)&Bs[wn * 32 + n * 16 + c][kk * 32 + g * 8];
            #pragma unroll
            for (int m = 0; m < 4; ++m)
                #pragma unroll
                for (int n = 0; n < 2; ++n)
                    acc[m][n] = __builtin_amdgcn_mfma_f32_16x16x32_bf16(a[m], bb[n], acc[m][n], 0, 0, 0);
        }
        __syncthreads();
    }
    #pragma unroll
    for (int n = 0; n < 2; ++n) {
        const int col = n0 + wn * 32 + n * 16 + c;
        const float bval = bias[col];
        #pragma unroll
        for (int m = 0; m < 4; ++m) {
            const int row0 = m0 + wm * 64 + m * 16 + g * 4;
            #pragma unroll
            for (int r = 0; r < 4; ++r)
                C[(size_t)(row0 + r) * D_ + col] = bf16_rne(acc[m][n][r] + bval);
        }
    }
}

// ---------------- final projection: 64x64 tile, 256 threads, bf16 A, f32 out ----------------
__global__ __launch_bounds__(256) void out_gemm_kernel(
    const unsigned short* __restrict__ A, const float* __restrict__ W,
    const float* __restrict__ bias, float* __restrict__ C)
{
    __shared__ unsigned short As[64][72];
    __shared__ unsigned short Bs[64][72];
    const int tid = threadIdx.x;
    const int w = tid >> 6, lane = tid & 63;
    const int g = lane >> 4, c = lane & 15;
    const int wm = w >> 1, wn = w & 1;        // 2x2 waves, wave tile 32x32
    const int m0 = blockIdx.y * 64, n0 = blockIdx.x * 64;
    const int trow = tid >> 2;                // 0..63
    const int tcol = (tid & 3) * 16;

    f32x4 acc[2][2];
    #pragma unroll
    for (int m = 0; m < 2; ++m)
        #pragma unroll
        for (int n = 0; n < 2; ++n)
            acc[m][n] = f32x4{0.f, 0.f, 0.f, 0.f};

    for (int k0 = 0; k0 < D_; k0 += 64) {
        {
            const unsigned short* ap = A + (size_t)(m0 + trow) * D_ + k0 + tcol;
            *(ushort8v*)&As[trow][tcol]     = *(const ushort8v*)ap;
            *(ushort8v*)&As[trow][tcol + 8] = *(const ushort8v*)(ap + 8);
            const float* wp = W + (size_t)(n0 + trow) * D_ + k0 + tcol;
            float4 f0 = *(const float4*)(wp);
            float4 f1 = *(const float4*)(wp + 4);
            float4 f2 = *(const float4*)(wp + 8);
            float4 f3 = *(const float4*)(wp + 12);
            ushort8v u0, u1;
            u0[0]=bf16_rne(f0.x); u0[1]=bf16_rne(f0.y); u0[2]=bf16_rne(f0.z); u0[3]=bf16_rne(f0.w);
            u0[4]=bf16_rne(f1.x); u0[5]=bf16_rne(f1.y); u0[6]=bf16_rne(f1.z); u0[7]=bf16_rne(f1.w);
            u1[0]=bf16_rne(f2.x); u1[1]=bf16_rne(f2.y); u1[2]=bf16_rne(f2.z); u1[3]=bf16_rne(f2.w);
            u1[4]=bf16_rne(f3.x); u1[5]=bf16_rne(f3.y); u1[6]=bf16_rne(f3.z); u1[7]=bf16_rne(f3.w);
            *(ushort8v*)&Bs[trow][tcol]     = u0;
            *(ushort8v*)&Bs[trow][tcol + 8] = u1;
        }
        __syncthreads();
        #pragma unroll
        for (int kk = 0; kk < 2; ++kk) {
            short8 a[2], bb[2];
            #pragma unroll
            for (int m = 0; m < 2; ++m) a[m]  = *(const short8*)&As[wm * 32 + m * 16 + c][kk * 32 + g * 8];
            #pragma unroll
            for (int n = 0; n < 2; ++n) bb[n] = *(const short8*)&Bs[wn * 32 + n * 16 + c][kk * 32 + g * 8];
            #pragma unroll
            for (int m = 0; m < 2; ++m)
                #pragma unroll
                for (int n = 0; n < 2; ++n)
                    acc[m][n] = __builtin_amdgcn_mfma_f32_16x16x32_bf16(a[m], bb[n], acc[m][n], 0, 0, 0);
        }
        __syncthreads();
    }
    #pragma unroll
    for (int n = 0; n < 2; ++n) {
        const int col = n0 + wn * 32 + n * 16 + c;
        const float bval = bias[col];
        #pragma unroll
        for (int m = 0; m < 2; ++m) {
            const int row0 = m0 + wm * 32 + m * 16 + g * 4;
            #pragma unroll
            for (int r = 0; r < 4; ++r)
                C[(size_t)(row0 + r) * D_ + col] = acc[m][n][r] + bval;
        }
    }
}

// ---------------- fused attention, S^T layout ----------------
// S^T = mfma(K-frag, Q-frag): lane (g,c) holds S[key=k0+n*16+g*4+r][q=qrow0+c].
// Per-lane: one q row -> scalar m/l state, float4 score stores, 2-shuffle reduce.
__global__ __launch_bounds__(256) void attn_kernel(
    const unsigned short* __restrict__ Qb, const unsigned short* __restrict__ Kb,
    const unsigned short* __restrict__ Vb, const int* __restrict__ mask,
    const unsigned int* __restrict__ bits, const float* __restrict__ colsum,
    float* __restrict__ scores, unsigned short* __restrict__ X)
{
    const int qt = blockIdx.x;
    const int h  = blockIdx.y;
    const int b  = blockIdx.z;
    const int tid = threadIdx.x;
    const int w = tid >> 6, lane = tid & 63;
    const int g = lane >> 4, c = lane & 15;

    __shared__ unsigned short VT_lds[2][64][72];   // [buf][dk][k] transposed V tile
    __shared__ unsigned short P_lds[4][16][72];    // [wave][q][k] bf16 P
    __shared__ float fac_lds[S_];                  // per-key: masked ? -1 : 1/colcount

    // build fac table once per block
    for (int i = tid; i < S_; i += 256) {
        const int km = mask[b * S_ + i];
        const float cnt = colsum[b * S_ + i];
        fac_lds[i] = (km == 0) ? -1.f : ((cnt > 0.f) ? (1.f / cnt) : 0.f);
    }

    const int qrow0 = qt * 64 + w * 16;
    const unsigned short* qptr = Qb + ((size_t)b * S_ + qrow0 + c) * D_ + h * DK_;
    const short8 qf0 = *(const short8*)(qptr + g * 8);
    const short8 qf1 = *(const short8*)(qptr + 32 + g * 8);

    float mrow = -INFINITY, lrow = 0.f;   // per-lane state for q = qrow0 + c
    f32x4 o[4];
    #pragma unroll
    for (int n = 0; n < 4; ++n) o[n] = f32x4{0.f, 0.f, 0.f, 0.f};

    float* srow = scores + ((((size_t)(b * H_ + h)) * S_ + qrow0 + c) * S_);
    const unsigned int* brow = bits + ((size_t)b * S_ + qrow0 + c) * KW_;
    const int kr = tid & 63, half = tid >> 6;
    const unsigned short* vrow = Vb + ((size_t)b * S_ + kr) * D_ + h * DK_ + half * 16;

    // prologue: stage V tile 0 into buf 0
    {
        short8 v0 = *(const short8*)vrow;
        short8 v1 = *(const short8*)(vrow + 8);
        #pragma unroll
        for (int j = 0; j < 8; ++j) {
            VT_lds[0][half * 16 + j][kr]     = (unsigned short)v0[j];
            VT_lds[0][half * 16 + 8 + j][kr] = (unsigned short)v1[j];
        }
    }
    __syncthreads();   // fac table + V tile 0 ready

    for (int kt = 0; kt < NT_; ++kt) {
        const int k0 = kt * 64;
        const int cur = kt & 1;
        const bool have_next = (kt + 1) < NT_;

        // issue next V tile's global loads early (latency hidden under QK/softmax)
        short8 nv0, nv1;
        if (have_next) {
            const unsigned short* vs = vrow + (size_t)(k0 + 64) * D_;
            nv0 = *(const short8*)vs;
            nv1 = *(const short8*)(vs + 8);
        }

        // ---- S^T = K Q^T ----
        f32x4 sacc[4];
        #pragma unroll
        for (int n = 0; n < 4; ++n) sacc[n] = f32x4{0.f, 0.f, 0.f, 0.f};
        #pragma unroll
        for (int n = 0; n < 4; ++n) {
            const unsigned short* kp = Kb + ((size_t)b * S_ + k0 + n * 16 + c) * D_ + h * DK_;
            short8 kf0 = *(const short8*)(kp + g * 8);
            short8 kf1 = *(const short8*)(kp + 32 + g * 8);
            sacc[n] = __builtin_amdgcn_mfma_f32_16x16x32_bf16(kf0, qf0, sacc[n], 0, 0, 0);
            sacc[n] = __builtin_amdgcn_mfma_f32_16x16x32_bf16(kf1, qf1, sacc[n], 0, 0, 0);
        }

        // ---- factor/mask + scores (float4) + tile max ----
        const unsigned int w0 = brow[(k0 >> 5)];
        const unsigned int w1 = brow[(k0 >> 5) + 1];
        float pmax = -INFINITY;
        f32x4 sv[4];
        #pragma unroll
        for (int n = 0; n < 4; ++n) {
            const f32x4 fv = *(const f32x4*)&fac_lds[k0 + n * 16 + g * 4];
            const unsigned int wsel = (n < 2) ? w0 : w1;
            #pragma unroll
            for (int r = 0; r < 4; ++r) {
                const int kl = n * 16 + g * 4 + r;           // 0..63
                const float f = fv[r];
                const float icnt = fmaxf(f, 0.f);
                const float bit = (float)((wsel >> (kl & 31)) & 1u);
                float s = sacc[n][r] * 0.125f * (1.f + bit * icnt);
                s = (f < 0.f) ? -1e9f : s;
                sv[n][r] = s;
                pmax = fmaxf(pmax, s);
            }
            *(f32x4*)&srow[k0 + n * 16 + g * 4] = sv[n];
        }

        // ---- online softmax (per-lane scalar state) ----
        pmax = fmaxf(pmax, __shfl_xor(pmax, 16));
        pmax = fmaxf(pmax, __shfl_xor(pmax, 32));
        const float nm = fmaxf(mrow, pmax);
        const float scq = __expf(mrow - nm);    // exp(-inf)=0 first tile
        mrow = nm;
        lrow *= scq;
        // redistribute scale to O rows (q = qrow0 + g*4 + r held by lane c = g*4+r)
        float sc_o[4];
        #pragma unroll
        for (int r = 0; r < 4; ++r) sc_o[r] = __shfl(scq, (lane & 48) | (g * 4 + r));
        #pragma unroll
        for (int n = 0; n < 4; ++n)
            #pragma unroll
            for (int r = 0; r < 4; ++r) o[n][r] *= sc_o[r];

        // ---- P = exp(S - m), vectorized transposed write ----
        #pragma unroll
        for (int n = 0; n < 4; ++n) {
            ushort4v pu;
            #pragma unroll
            for (int r = 0; r < 4; ++r) {
                const float p = __expf(sv[n][r] - mrow);
                lrow += p;
                pu[r] = bf16_rne(p);
            }
            *(ushort4v*)&P_lds[w][c][n * 16 + g * 4] = pu;   // wave-private
        }

        // ---- stage next V tile into other buffer ----
        if (have_next) {
            #pragma unroll
            for (int j = 0; j < 8; ++j) {
                VT_lds[cur ^ 1][half * 16 + j][kr]     = (unsigned short)nv0[j];
                VT_lds[cur ^ 1][half * 16 + 8 + j][kr] = (unsigned short)nv1[j];
            }
        }

        // ---- O += P V ----
        #pragma unroll
        for (int kk = 0; kk < 2; ++kk) {
            const short8 pa = *(const short8*)&P_lds[w][c][kk * 32 + g * 8];
            #pragma unroll
            for (int n = 0; n < 4; ++n) {
                const short8 vf = *(const short8*)&VT_lds[cur][n * 16 + c][kk * 32 + g * 8];
                o[n] = __builtin_amdgcn_mfma_f32_16x16x32_bf16(pa, vf, o[n], 0, 0, 0);
            }
        }
        __syncthreads();   // all waves done with VT_lds[cur] + next tile staged
    }

    // ---- finalize ----
    lrow += __shfl_xor(lrow, 16);
    lrow += __shfl_xor(lrow, 32);
    const float linv = 1.f / lrow;
    float linv_o[4];
    #pragma unroll
    for (int r = 0; r < 4; ++r) linv_o[r] = __shfl(linv, (lane & 48) | (g * 4 + r));
    #pragma unroll
    for (int n = 0; n < 4; ++n)
        #pragma unroll
        for (int r = 0; r < 4; ++r) {
            const size_t idx = ((size_t)b * S_ + qrow0 + g * 4 + r) * D_ + h * DK_ + n * 16 + c;
            X[idx] = bf16_rne(o[n][r] * linv_o[r]);
        }
}

extern "C" void kernel_launch(void* const* d_in, const int* in_sizes, int n_in,
                              void* d_out, int out_size, void* d_ws, size_t ws_size,
                              hipStream_t stream) {
    const float* query = (const float*)d_in[0];
    const float* key   = (const float*)d_in[1];
    const float* value = (const float*)d_in[2];
    const int*   mask  = (const int*)d_in[3];
    const float* mask1 = (const float*)d_in[4];
    const float* Wq = (const float*)d_in[5];
    const float* bq = (const float*)d_in[6];
    const float* Wk = (const float*)d_in[7];
    const float* bk = (const float*)d_in[8];
    const float* Wv = (const float*)d_in[9];
    const float* bv = (const float*)d_in[10];
    const float* Wo = (const float*)d_in[11];
    const float* bo = (const float*)d_in[12];

    float* ret_out    = (float*)d_out;               // f32 [B,S,D]
    float* scores_out = ret_out + RET_ELEMS;         // f32 [B,H,S,S]

    const size_t SZ = (size_t)B_ * S_ * D_;          // 3,145,728 elems
    // ws layout (~24.6 MiB): colsum(16K) | bits(576K) | Qb | Kb | Vb | Xb (bf16)
    float* colsum = (float*)d_ws;
    unsigned int* bits = (unsigned int*)((char*)d_ws + 16384);
    unsigned short* Qb = (unsigned short*)((char*)d_ws + 16384 + 589824);
    unsigned short* Kb = Qb + SZ;
    unsigned short* Vb = Kb + SZ;
    unsigned short* Xb = Vb + SZ;

    zero_colsum_kernel<<<12, 256, 0, stream>>>(colsum);
    colcount_kernel<<<dim3(B_, S_ / 256, 8), 256, 0, stream>>>(mask1, colsum);
    bitpack_kernel<<<(B_ * S_ * S_) / 256, 256, 0, stream>>>(mask1, bits);

    Proj p0{query, Wq, bq, Qb}, p1{key, Wk, bk, Kb}, p2{value, Wv, bv, Vb};
    qkv_gemm_kernel<<<dim3(D_ / 128, (B_ * S_) / 128, 3), 512, 0, stream>>>(p0, p1, p2);

    attn_kernel<<<dim3(S_ / 64, H_, B_), 256, 0, stream>>>(Qb, Kb, Vb, mask, bits, colsum, scores_out, Xb);

    out_gemm_kernel<<<dim3(D_ / 64, (B_ * S_) / 64), 256, 0, stream>>>(Xb, Wo, bo, ret_out);
}

// Round 7
// 240.549 us; speedup vs baseline: 1.4903x; 1.0099x over previous
//
#include <hip/hip_runtime.h>
#include <hip/hip_bf16.h>

#define B_ 2
#define S_ 1536
#define D_ 1024
#define H_ 16
#define DK_ 64
#define KW_ 48                 // S_/32 mask-bit words per row
#define NT_ 24                 // S_/64 key tiles

#define RET_ELEMS 3145728      // f32 elems: [B,S,D]

typedef __attribute__((ext_vector_type(8))) short short8;
typedef __attribute__((ext_vector_type(8))) unsigned short ushort8v;
typedef __attribute__((ext_vector_type(4))) unsigned short ushort4v;
typedef __attribute__((ext_vector_type(4))) float f32x4;

// hardware RNE f32->bf16 (1 instr vs 5-op bit math)
__device__ __forceinline__ unsigned short bf16_rne(float f) {
    return __builtin_bit_cast(unsigned short, __float2bfloat16(f));
}

// ---------------- column count of mask1 (sum over q axis) ----------------
__global__ void colcount_kernel(const float* __restrict__ mask1, float* __restrict__ colsum) {
    const int b   = blockIdx.x;
    const int col = blockIdx.y * 256 + threadIdx.x;
    const int q0  = blockIdx.z * (S_ / 8);
    const float* p = mask1 + ((size_t)b * S_ + q0) * S_ + col;
    float s = 0.f;
    #pragma unroll 8
    for (int q = 0; q < S_ / 8; ++q) s += p[(size_t)q * S_];
    atomicAdd(&colsum[b * S_ + col], s);   // integer-valued: exact, order-independent
}

// ---------------- pack mask1 into bits + zero colsum (runs before colcount) ----------------
__global__ void bitpack_kernel(const float* __restrict__ mask1, unsigned int* __restrict__ bits,
                               float* __restrict__ colsum) {
    if (blockIdx.x < 12) colsum[blockIdx.x * 256 + threadIdx.x] = 0.f;
    const size_t gid = (size_t)blockIdx.x * 256 + threadIdx.x;   // over B*S*S
    const float v = mask1[gid];
    const unsigned long long bal = __ballot(v != 0.f);
    const int l = threadIdx.x & 63;
    if (l == 0)       bits[gid >> 5] = (unsigned int)bal;
    else if (l == 32) bits[gid >> 5] = (unsigned int)(bal >> 32);
}

// ---------------- fused QKV projection GEMM: 128x128 tile, BK=64, 512 threads ----------------
struct Proj { const float* A; const float* W; const float* bias; unsigned short* C; };

__device__ __forceinline__ void cvt16(const float* src, unsigned short* dst) {
    float4 f0 = *(const float4*)(src);
    float4 f1 = *(const float4*)(src + 4);
    float4 f2 = *(const float4*)(src + 8);
    float4 f3 = *(const float4*)(src + 12);
    ushort8v u0, u1;
    u0[0]=bf16_rne(f0.x); u0[1]=bf16_rne(f0.y); u0[2]=bf16_rne(f0.z); u0[3]=bf16_rne(f0.w);
    u0[4]=bf16_rne(f1.x); u0[5]=bf16_rne(f1.y); u0[6]=bf16_rne(f1.z); u0[7]=bf16_rne(f1.w);
    u1[0]=bf16_rne(f2.x); u1[1]=bf16_rne(f2.y); u1[2]=bf16_rne(f2.z); u1[3]=bf16_rne(f2.w);
    u1[4]=bf16_rne(f3.x); u1[5]=bf16_rne(f3.y); u1[6]=bf16_rne(f3.z); u1[7]=bf16_rne(f3.w);
    *(ushort8v*)dst       = u0;
    *(ushort8v*)(dst + 8) = u1;
}

__global__ __launch_bounds__(512) void qkv_gemm_kernel(Proj p0, Proj p1, Proj p2) {
    const int z = blockIdx.z;
    const float* A    = z == 0 ? p0.A    : (z == 1 ? p1.A    : p2.A);
    const float* W    = z == 0 ? p0.W    : (z == 1 ? p1.W    : p2.W);
    const float* bias = z == 0 ? p0.bias : (z == 1 ? p1.bias : p2.bias);
    unsigned short* C = z == 0 ? p0.C    : (z == 1 ? p1.C    : p2.C);

    __shared__ unsigned short As[128][72];
    __shared__ unsigned short Bs[128][72];
    const int tid = threadIdx.x;
    const int w = tid >> 6, lane = tid & 63;
    const int g = lane >> 4, c = lane & 15;
    const int wm = w >> 2, wn = w & 3;        // 2x4 waves, wave tile 64x32
    const int m0 = blockIdx.y * 128, n0 = blockIdx.x * 128;
    const int trow = tid >> 2;                // 0..127
    const int tcol = (tid & 3) * 16;          // 0,16,32,48

    f32x4 acc[4][2];
    #pragma unroll
    for (int m = 0; m < 4; ++m)
        #pragma unroll
        for (int n = 0; n < 2; ++n)
            acc[m][n] = f32x4{0.f, 0.f, 0.f, 0.f};

    for (int k0 = 0; k0 < D_; k0 += 64) {
        cvt16(A + (size_t)(m0 + trow) * D_ + k0 + tcol, &As[trow][tcol]);
        cvt16(W + (size_t)(n0 + trow) * D_ + k0 + tcol, &Bs[trow][tcol]);
        __syncthreads();
        #pragma unroll
        for (int kk = 0; kk < 2; ++kk) {
            short8 a[4], bb[2];
            #pragma unroll
            for (int m = 0; m < 4; ++m) a[m]  = *(const short8*)&As[wm * 64 + m * 16 + c][kk * 32 + g * 8];
            #pragma unroll
            for (int n = 0; n < 2; ++n) bb[n] = *(const short8*)&Bs[wn * 32 + n * 16 + c][kk * 32 + g * 8];
            #pragma unroll
            for (int m = 0; m < 4; ++m)
                #pragma unroll
                for (int n = 0; n < 2; ++n)
                    acc[m][n] = __builtin_amdgcn_mfma_f32_16x16x32_bf16(a[m], bb[n], acc[m][n], 0, 0, 0);
        }
        __syncthreads();
    }
    #pragma unroll
    for (int n = 0; n < 2; ++n) {
        const int col = n0 + wn * 32 + n * 16 + c;
        const float bval = bias[col];
        #pragma unroll
        for (int m = 0; m < 4; ++m) {
            const int row0 = m0 + wm * 64 + m * 16 + g * 4;
            #pragma unroll
            for (int r = 0; r < 4; ++r)
                C[(size_t)(row0 + r) * D_ + col] = bf16_rne(acc[m][n][r] + bval);
        }
    }
}

// ---------------- final projection: 64x64 tile, 256 threads, bf16 A, f32 out ----------------
__global__ __launch_bounds__(256) void out_gemm_kernel(
    const unsigned short* __restrict__ A, const float* __restrict__ W,
    const float* __restrict__ bias, float* __restrict__ C)
{
    __shared__ unsigned short As[64][72];
    __shared__ unsigned short Bs[64][72];
    const int tid = threadIdx.x;
    const int w = tid >> 6, lane = tid & 63;
    const int g = lane >> 4, c = lane & 15;
    const int wm = w >> 1, wn = w & 1;        // 2x2 waves, wave tile 32x32
    const int m0 = blockIdx.y * 64, n0 = blockIdx.x * 64;
    const int trow = tid >> 2;                // 0..63
    const int tcol = (tid & 3) * 16;

    f32x4 acc[2][2];
    #pragma unroll
    for (int m = 0; m < 2; ++m)
        #pragma unroll
        for (int n = 0; n < 2; ++n)
            acc[m][n] = f32x4{0.f, 0.f, 0.f, 0.f};

    for (int k0 = 0; k0 < D_; k0 += 64) {
        {
            const unsigned short* ap = A + (size_t)(m0 + trow) * D_ + k0 + tcol;
            *(ushort8v*)&As[trow][tcol]     = *(const ushort8v*)ap;
            *(ushort8v*)&As[trow][tcol + 8] = *(const ushort8v*)(ap + 8);
            cvt16(W + (size_t)(n0 + trow) * D_ + k0 + tcol, &Bs[trow][tcol]);
        }
        __syncthreads();
        #pragma unroll
        for (int kk = 0; kk < 2; ++kk) {
            short8 a[2], bb[2];
            #pragma unroll
            for (int m = 0; m < 2; ++m) a[m]  = *(const short8*)&As[wm * 32 + m * 16 + c][kk * 32 + g * 8];
            #pragma unroll
            for (int n = 0; n < 2; ++n) bb[n] = *(const short8*)&Bs[wn * 32 + n * 16 + c][kk * 32 + g * 8];
            #pragma unroll
            for (int m = 0; m < 2; ++m)
                #pragma unroll
                for (int n = 0; n < 2; ++n)
                    acc[m][n] = __builtin_amdgcn_mfma_f32_16x16x32_bf16(a[m], bb[n], acc[m][n], 0, 0, 0);
        }
        __syncthreads();
    }
    #pragma unroll
    for (int n = 0; n < 2; ++n) {
        const int col = n0 + wn * 32 + n * 16 + c;
        const float bval = bias[col];
        #pragma unroll
        for (int m = 0; m < 2; ++m) {
            const int row0 = m0 + wm * 32 + m * 16 + g * 4;
            #pragma unroll
            for (int r = 0; r < 4; ++r)
                C[(size_t)(row0 + r) * D_ + col] = acc[m][n][r] + bval;
        }
    }
}

// ---------------- fused attention, S^T layout ----------------
// S^T = mfma(K-frag, Q-frag): lane (g,c) holds S[key=k0+n*16+g*4+r][q=qrow0+c].
// Per-lane: one q row -> scalar m/l state, float4 nt score stores, 2-shuffle reduce.
__global__ __launch_bounds__(256) void attn_kernel(
    const unsigned short* __restrict__ Qb, const unsigned short* __restrict__ Kb,
    const unsigned short* __restrict__ Vb, const int* __restrict__ mask,
    const unsigned int* __restrict__ bits, const float* __restrict__ colsum,
    float* __restrict__ scores, unsigned short* __restrict__ X)
{
    const int qt = blockIdx.x;
    const int h  = blockIdx.y;
    const int b  = blockIdx.z;
    const int tid = threadIdx.x;
    const int w = tid >> 6, lane = tid & 63;
    const int g = lane >> 4, c = lane & 15;

    __shared__ unsigned short VT_lds[2][64][72];   // [buf][dk][k] transposed V tile
    __shared__ unsigned short P_lds[4][16][72];    // [wave][q][k] bf16 P
    __shared__ float fac_lds[S_];                  // per-key: masked ? -1 : 1/colcount

    // build fac table once per block
    for (int i = tid; i < S_; i += 256) {
        const int km = mask[b * S_ + i];
        const float cnt = colsum[b * S_ + i];
        fac_lds[i] = (km == 0) ? -1.f : ((cnt > 0.f) ? (1.f / cnt) : 0.f);
    }

    const int qrow0 = qt * 64 + w * 16;
    const unsigned short* qptr = Qb + ((size_t)b * S_ + qrow0 + c) * D_ + h * DK_;
    const short8 qf0 = *(const short8*)(qptr + g * 8);
    const short8 qf1 = *(const short8*)(qptr + 32 + g * 8);

    float mrow = -INFINITY, lrow = 0.f;   // per-lane state for q = qrow0 + c
    f32x4 o[4];
    #pragma unroll
    for (int n = 0; n < 4; ++n) o[n] = f32x4{0.f, 0.f, 0.f, 0.f};

    float* srow = scores + ((((size_t)(b * H_ + h)) * S_ + qrow0 + c) * S_);
    const unsigned int* brow = bits + ((size_t)b * S_ + qrow0 + c) * KW_;
    const int kr = tid & 63, half = tid >> 6;
    const unsigned short* vrow = Vb + ((size_t)b * S_ + kr) * D_ + h * DK_ + half * 16;

    // prologue: stage V tile 0 into buf 0
    {
        short8 v0 = *(const short8*)vrow;
        short8 v1 = *(const short8*)(vrow + 8);
        #pragma unroll
        for (int j = 0; j < 8; ++j) {
            VT_lds[0][half * 16 + j][kr]     = (unsigned short)v0[j];
            VT_lds[0][half * 16 + 8 + j][kr] = (unsigned short)v1[j];
        }
    }
    __syncthreads();   // fac table + V tile 0 ready

    for (int kt = 0; kt < NT_; ++kt) {
        const int k0 = kt * 64;
        const int cur = kt & 1;
        const bool have_next = (kt + 1) < NT_;

        // issue next V tile's global loads early (latency hidden under QK/softmax)
        short8 nv0, nv1;
        if (have_next) {
            const unsigned short* vs = vrow + (size_t)(k0 + 64) * D_;
            nv0 = *(const short8*)vs;
            nv1 = *(const short8*)(vs + 8);
        }

        // ---- S^T = K Q^T ----
        f32x4 sacc[4];
        #pragma unroll
        for (int n = 0; n < 4; ++n) sacc[n] = f32x4{0.f, 0.f, 0.f, 0.f};
        #pragma unroll
        for (int n = 0; n < 4; ++n) {
            const unsigned short* kp = Kb + ((size_t)b * S_ + k0 + n * 16 + c) * D_ + h * DK_;
            short8 kf0 = *(const short8*)(kp + g * 8);
            short8 kf1 = *(const short8*)(kp + 32 + g * 8);
            sacc[n] = __builtin_amdgcn_mfma_f32_16x16x32_bf16(kf0, qf0, sacc[n], 0, 0, 0);
            sacc[n] = __builtin_amdgcn_mfma_f32_16x16x32_bf16(kf1, qf1, sacc[n], 0, 0, 0);
        }

        // ---- factor/mask + scores (nontemporal float4) + tile max ----
        const unsigned int w0 = brow[(k0 >> 5)];
        const unsigned int w1 = brow[(k0 >> 5) + 1];
        float pmax = -INFINITY;
        f32x4 sv[4];
        #pragma unroll
        for (int n = 0; n < 4; ++n) {
            const f32x4 fv = *(const f32x4*)&fac_lds[k0 + n * 16 + g * 4];
            const unsigned int wsel = (n < 2) ? w0 : w1;
            #pragma unroll
            for (int r = 0; r < 4; ++r) {
                const int kl = n * 16 + g * 4 + r;           // 0..63
                const float f = fv[r];
                const float icnt = fmaxf(f, 0.f);
                const float bit = (float)((wsel >> (kl & 31)) & 1u);
                float s = sacc[n][r] * 0.125f * (1.f + bit * icnt);
                s = (f < 0.f) ? -1e9f : s;
                sv[n][r] = s;
                pmax = fmaxf(pmax, s);
            }
            __builtin_nontemporal_store(sv[n], (f32x4*)&srow[k0 + n * 16 + g * 4]);
        }

        // ---- online softmax (per-lane scalar state) ----
        pmax = fmaxf(pmax, __shfl_xor(pmax, 16));
        pmax = fmaxf(pmax, __shfl_xor(pmax, 32));
        const float nm = fmaxf(mrow, pmax);
        const float scq = __expf(mrow - nm);    // exp(-inf)=0 first tile
        mrow = nm;
        lrow *= scq;
        // redistribute scale to O rows (q = qrow0 + g*4 + r held by lane c = g*4+r)
        float sc_o[4];
        #pragma unroll
        for (int r = 0; r < 4; ++r) sc_o[r] = __shfl(scq, (lane & 48) | (g * 4 + r));
        #pragma unroll
        for (int n = 0; n < 4; ++n)
            #pragma unroll
            for (int r = 0; r < 4; ++r) o[n][r] *= sc_o[r];

        // ---- P = exp(S - m), vectorized transposed write ----
        #pragma unroll
        for (int n = 0; n < 4; ++n) {
            ushort4v pu;
            #pragma unroll
            for (int r = 0; r < 4; ++r) {
                const float p = __expf(sv[n][r] - mrow);
                lrow += p;
                pu[r] = bf16_rne(p);
            }
            *(ushort4v*)&P_lds[w][c][n * 16 + g * 4] = pu;   // wave-private
        }

        // ---- stage next V tile into other buffer ----
        if (have_next) {
            #pragma unroll
            for (int j = 0; j < 8; ++j) {
                VT_lds[cur ^ 1][half * 16 + j][kr]     = (unsigned short)nv0[j];
                VT_lds[cur ^ 1][half * 16 + 8 + j][kr] = (unsigned short)nv1[j];
            }
        }

        // ---- O += P V ----
        #pragma unroll
        for (int kk = 0; kk < 2; ++kk) {
            const short8 pa = *(const short8*)&P_lds[w][c][kk * 32 + g * 8];
            #pragma unroll
            for (int n = 0; n < 4; ++n) {
                const short8 vf = *(const short8*)&VT_lds[cur][n * 16 + c][kk * 32 + g * 8];
                o[n] = __builtin_amdgcn_mfma_f32_16x16x32_bf16(pa, vf, o[n], 0, 0, 0);
            }
        }
        __syncthreads();   // all waves done with VT_lds[cur] + next tile staged
    }

    // ---- finalize ----
    lrow += __shfl_xor(lrow, 16);
    lrow += __shfl_xor(lrow, 32);
    const float linv = 1.f / lrow;
    float linv_o[4];
    #pragma unroll
    for (int r = 0; r < 4; ++r) linv_o[r] = __shfl(linv, (lane & 48) | (g * 4 + r));
    #pragma unroll
    for (int n = 0; n < 4; ++n)
        #pragma unroll
        for (int r = 0; r < 4; ++r) {
            const size_t idx = ((size_t)b * S_ + qrow0 + g * 4 + r) * D_ + h * DK_ + n * 16 + c;
            X[idx] = bf16_rne(o[n][r] * linv_o[r]);
        }
}

extern "C" void kernel_launch(void* const* d_in, const int* in_sizes, int n_in,
                              void* d_out, int out_size, void* d_ws, size_t ws_size,
                              hipStream_t stream) {
    const float* query = (const float*)d_in[0];
    const float* key   = (const float*)d_in[1];
    const float* value = (const float*)d_in[2];
    const int*   mask  = (const int*)d_in[3];
    const float* mask1 = (const float*)d_in[4];
    const float* Wq = (const float*)d_in[5];
    const float* bq = (const float*)d_in[6];
    const float* Wk = (const float*)d_in[7];
    const float* bk = (const float*)d_in[8];
    const float* Wv = (const float*)d_in[9];
    const float* bv = (const float*)d_in[10];
    const float* Wo = (const float*)d_in[11];
    const float* bo = (const float*)d_in[12];

    float* ret_out    = (float*)d_out;               // f32 [B,S,D]
    float* scores_out = ret_out + RET_ELEMS;         // f32 [B,H,S,S]

    const size_t SZ = (size_t)B_ * S_ * D_;          // 3,145,728 elems
    // ws layout (~24.6 MiB): colsum(16K) | bits(576K) | Qb | Kb | Vb | Xb (bf16)
    float* colsum = (float*)d_ws;
    unsigned int* bits = (unsigned int*)((char*)d_ws + 16384);
    unsigned short* Qb = (unsigned short*)((char*)d_ws + 16384 + 589824);
    unsigned short* Kb = Qb + SZ;
    unsigned short* Vb = Kb + SZ;
    unsigned short* Xb = Vb + SZ;

    bitpack_kernel<<<(B_ * S_ * S_) / 256, 256, 0, stream>>>(mask1, bits, colsum);
    colcount_kernel<<<dim3(B_, S_ / 256, 8), 256, 0, stream>>>(mask1, colsum);

    Proj p0{query, Wq, bq, Qb}, p1{key, Wk, bk, Kb}, p2{value, Wv, bv, Vb};
    qkv_gemm_kernel<<<dim3(D_ / 128, (B_ * S_) / 128, 3), 512, 0, stream>>>(p0, p1, p2);

    attn_kernel<<<dim3(S_ / 64, H_, B_), 256, 0, stream>>>(Qb, Kb, Vb, mask, bits, colsum, scores_out, Xb);

    out_gemm_kernel<<<dim3(D_ / 64, (B_ * S_) / 64), 256, 0, stream>>>(Xb, Wo, bo, ret_out);
}

// Round 8
// 235.015 us; speedup vs baseline: 1.5254x; 1.0235x over previous
//
#include <hip/hip_runtime.h>
#include <hip/hip_bf16.h>

#define B_ 2
#define S_ 1536
#define D_ 1024
#define H_ 16
#define DK_ 64
#define KW_ 48                 // S_/32 mask-bit words per row
#define NT_ 24                 // S_/64 key tiles

#define RET_ELEMS 3145728      // f32 elems: [B,S,D]

typedef __attribute__((ext_vector_type(8))) short short8;
typedef __attribute__((ext_vector_type(8))) unsigned short ushort8v;
typedef __attribute__((ext_vector_type(4))) unsigned short ushort4v;
typedef __attribute__((ext_vector_type(4))) float f32x4;

__device__ __forceinline__ unsigned short bf16_rne(float f) {
    return __builtin_bit_cast(unsigned short, __float2bfloat16(f));
}

// ---------------- f32 -> bf16 bulk convert (7 arrays in one launch) ----------------
struct CvtJobs {
    const float* src[7];
    unsigned short* dst[7];
    int n8[7];                 // elements/8
};

__global__ __launch_bounds__(256) void cvt_kernel(CvtJobs j) {
    const int y = blockIdx.y;
    const int i = blockIdx.x * 256 + threadIdx.x;
    if (i >= j.n8[y]) return;
    const float* s = j.src[y] + (size_t)i * 8;
    float4 f0 = *(const float4*)s;
    float4 f1 = *(const float4*)(s + 4);
    ushort8v u;
    u[0]=bf16_rne(f0.x); u[1]=bf16_rne(f0.y); u[2]=bf16_rne(f0.z); u[3]=bf16_rne(f0.w);
    u[4]=bf16_rne(f1.x); u[5]=bf16_rne(f1.y); u[6]=bf16_rne(f1.z); u[7]=bf16_rne(f1.w);
    *(ushort8v*)(j.dst[y] + (size_t)i * 8) = u;
}

// ---------------- pack mask1 into bits: word[(b*S+q)*48 + k/32] ----------------
__global__ void bitpack_kernel(const float* __restrict__ mask1, unsigned int* __restrict__ bits) {
    const size_t gid = (size_t)blockIdx.x * 256 + threadIdx.x;   // over B*S*S
    const float v = mask1[gid];
    const unsigned long long bal = __ballot(v != 0.f);
    const int l = threadIdx.x & 63;
    if (l == 0)       bits[gid >> 5] = (unsigned int)bal;
    else if (l == 32) bits[gid >> 5] = (unsigned int)(bal >> 32);
}

// ---------------- column count from bits (reads 2.4 MB instead of 18.9 MB) ----------------
__global__ void colcount_bits_kernel(const unsigned int* __restrict__ bits, float* __restrict__ colsum) {
    const int b   = blockIdx.x >> 3;
    const int col = ((blockIdx.x & 7) * 256 + threadIdx.x) & (S_ - 1);
    const int wword = col >> 5, bit = col & 31;
    const unsigned int* p = bits + (size_t)b * S_ * KW_ + wword;
    int s = 0;
    for (int q = 0; q < S_; ++q) s += (p[(size_t)q * KW_] >> bit) & 1u;
    colsum[b * S_ + col] = (float)s;
}

// ---------------- fused QKV projection GEMM: bf16 in, 128x128 tile, BK=64, 512 threads ----------------
struct Proj { const unsigned short* A; const unsigned short* W; const float* bias; unsigned short* C; };

__global__ __launch_bounds__(512) void qkv_gemm_kernel(Proj p0, Proj p1, Proj p2) {
    const int z = blockIdx.z;
    const unsigned short* A = z == 0 ? p0.A    : (z == 1 ? p1.A    : p2.A);
    const unsigned short* W = z == 0 ? p0.W    : (z == 1 ? p1.W    : p2.W);
    const float* bias       = z == 0 ? p0.bias : (z == 1 ? p1.bias : p2.bias);
    unsigned short* C       = z == 0 ? p0.C    : (z == 1 ? p1.C    : p2.C);

    __shared__ unsigned short As[128][72];
    __shared__ unsigned short Bs[128][72];
    const int tid = threadIdx.x;
    const int w = tid >> 6, lane = tid & 63;
    const int g = lane >> 4, c = lane & 15;
    const int wm = w >> 2, wn = w & 3;        // 2x4 waves, wave tile 64x32
    const int m0 = blockIdx.y * 128, n0 = blockIdx.x * 128;
    const int trow = tid >> 2;                // 0..127
    const int tcol = (tid & 3) * 16;          // 0,16,32,48

    f32x4 acc[4][2];
    #pragma unroll
    for (int m = 0; m < 4; ++m)
        #pragma unroll
        for (int n = 0; n < 2; ++n)
            acc[m][n] = f32x4{0.f, 0.f, 0.f, 0.f};

    for (int k0 = 0; k0 < D_; k0 += 64) {
        {
            const unsigned short* ap = A + (size_t)(m0 + trow) * D_ + k0 + tcol;
            *(ushort8v*)&As[trow][tcol]     = *(const ushort8v*)ap;
            *(ushort8v*)&As[trow][tcol + 8] = *(const ushort8v*)(ap + 8);
            const unsigned short* wp = W + (size_t)(n0 + trow) * D_ + k0 + tcol;
            *(ushort8v*)&Bs[trow][tcol]     = *(const ushort8v*)wp;
            *(ushort8v*)&Bs[trow][tcol + 8] = *(const ushort8v*)(wp + 8);
        }
        __syncthreads();
        #pragma unroll
        for (int kk = 0; kk < 2; ++kk) {
            short8 a[4], bb[2];
            #pragma unroll
            for (int m = 0; m < 4; ++m) a[m]  = *(const short8*)&As[wm * 64 + m * 16 + c][kk * 32 + g * 8];
            #pragma unroll
            for (int n = 0; n < 2; ++n) bb[n] = *(const short8*)&Bs[wn * 32 + n * 16 + c][kk * 32 + g * 8];
            #pragma unroll
            for (int m = 0; m < 4; ++m)
                #pragma unroll
                for (int n = 0; n < 2; ++n)
                    acc[m][n] = __builtin_amdgcn_mfma_f32_16x16x32_bf16(a[m], bb[n], acc[m][n], 0, 0, 0);
        }
        __syncthreads();
    }
    #pragma unroll
    for (int n = 0; n < 2; ++n) {
        const int col = n0 + wn * 32 + n * 16 + c;
        const float bval = bias[col];
        #pragma unroll
        for (int m = 0; m < 4; ++m) {
            const int row0 = m0 + wm * 64 + m * 16 + g * 4;
            #pragma unroll
            for (int r = 0; r < 4; ++r)
                C[(size_t)(row0 + r) * D_ + col] = bf16_rne(acc[m][n][r] + bval);
        }
    }
}

// ---------------- final projection: 64x64 tile, 256 threads, bf16 in, f32 out ----------------
__global__ __launch_bounds__(256) void out_gemm_kernel(
    const unsigned short* __restrict__ A, const unsigned short* __restrict__ W,
    const float* __restrict__ bias, float* __restrict__ C)
{
    __shared__ unsigned short As[64][72];
    __shared__ unsigned short Bs[64][72];
    const int tid = threadIdx.x;
    const int w = tid >> 6, lane = tid & 63;
    const int g = lane >> 4, c = lane & 15;
    const int wm = w >> 1, wn = w & 1;        // 2x2 waves, wave tile 32x32
    const int m0 = blockIdx.y * 64, n0 = blockIdx.x * 64;
    const int trow = tid >> 2;                // 0..63
    const int tcol = (tid & 3) * 16;

    f32x4 acc[2][2];
    #pragma unroll
    for (int m = 0; m < 2; ++m)
        #pragma unroll
        for (int n = 0; n < 2; ++n)
            acc[m][n] = f32x4{0.f, 0.f, 0.f, 0.f};

    for (int k0 = 0; k0 < D_; k0 += 64) {
        {
            const unsigned short* ap = A + (size_t)(m0 + trow) * D_ + k0 + tcol;
            *(ushort8v*)&As[trow][tcol]     = *(const ushort8v*)ap;
            *(ushort8v*)&As[trow][tcol + 8] = *(const ushort8v*)(ap + 8);
            const unsigned short* wp = W + (size_t)(n0 + trow) * D_ + k0 + tcol;
            *(ushort8v*)&Bs[trow][tcol]     = *(const ushort8v*)wp;
            *(ushort8v*)&Bs[trow][tcol + 8] = *(const ushort8v*)(wp + 8);
        }
        __syncthreads();
        #pragma unroll
        for (int kk = 0; kk < 2; ++kk) {
            short8 a[2], bb[2];
            #pragma unroll
            for (int m = 0; m < 2; ++m) a[m]  = *(const short8*)&As[wm * 32 + m * 16 + c][kk * 32 + g * 8];
            #pragma unroll
            for (int n = 0; n < 2; ++n) bb[n] = *(const short8*)&Bs[wn * 32 + n * 16 + c][kk * 32 + g * 8];
            #pragma unroll
            for (int m = 0; m < 2; ++m)
                #pragma unroll
                for (int n = 0; n < 2; ++n)
                    acc[m][n] = __builtin_amdgcn_mfma_f32_16x16x32_bf16(a[m], bb[n], acc[m][n], 0, 0, 0);
        }
        __syncthreads();
    }
    #pragma unroll
    for (int n = 0; n < 2; ++n) {
        const int col = n0 + wn * 32 + n * 16 + c;
        const float bval = bias[col];
        #pragma unroll
        for (int m = 0; m < 2; ++m) {
            const int row0 = m0 + wm * 32 + m * 16 + g * 4;
            #pragma unroll
            for (int r = 0; r < 4; ++r)
                C[(size_t)(row0 + r) * D_ + col] = acc[m][n][r] + bval;
        }
    }
}

// ---------------- fused attention, S^T layout (unchanged from round 7) ----------------
__global__ __launch_bounds__(256) void attn_kernel(
    const unsigned short* __restrict__ Qb, const unsigned short* __restrict__ Kb,
    const unsigned short* __restrict__ Vb, const int* __restrict__ mask,
    const unsigned int* __restrict__ bits, const float* __restrict__ colsum,
    float* __restrict__ scores, unsigned short* __restrict__ X)
{
    const int qt = blockIdx.x;
    const int h  = blockIdx.y;
    const int b  = blockIdx.z;
    const int tid = threadIdx.x;
    const int w = tid >> 6, lane = tid & 63;
    const int g = lane >> 4, c = lane & 15;

    __shared__ unsigned short VT_lds[2][64][72];   // [buf][dk][k] transposed V tile
    __shared__ unsigned short P_lds[4][16][72];    // [wave][q][k] bf16 P
    __shared__ float fac_lds[S_];                  // per-key: masked ? -1 : 1/colcount

    for (int i = tid; i < S_; i += 256) {
        const int km = mask[b * S_ + i];
        const float cnt = colsum[b * S_ + i];
        fac_lds[i] = (km == 0) ? -1.f : ((cnt > 0.f) ? (1.f / cnt) : 0.f);
    }

    const int qrow0 = qt * 64 + w * 16;
    const unsigned short* qptr = Qb + ((size_t)b * S_ + qrow0 + c) * D_ + h * DK_;
    const short8 qf0 = *(const short8*)(qptr + g * 8);
    const short8 qf1 = *(const short8*)(qptr + 32 + g * 8);

    float mrow = -INFINITY, lrow = 0.f;   // per-lane state for q = qrow0 + c
    f32x4 o[4];
    #pragma unroll
    for (int n = 0; n < 4; ++n) o[n] = f32x4{0.f, 0.f, 0.f, 0.f};

    float* srow = scores + ((((size_t)(b * H_ + h)) * S_ + qrow0 + c) * S_);
    const unsigned int* brow = bits + ((size_t)b * S_ + qrow0 + c) * KW_;
    const int kr = tid & 63, half = tid >> 6;
    const unsigned short* vrow = Vb + ((size_t)b * S_ + kr) * D_ + h * DK_ + half * 16;

    {
        short8 v0 = *(const short8*)vrow;
        short8 v1 = *(const short8*)(vrow + 8);
        #pragma unroll
        for (int j = 0; j < 8; ++j) {
            VT_lds[0][half * 16 + j][kr]     = (unsigned short)v0[j];
            VT_lds[0][half * 16 + 8 + j][kr] = (unsigned short)v1[j];
        }
    }
    __syncthreads();   // fac table + V tile 0 ready

    for (int kt = 0; kt < NT_; ++kt) {
        const int k0 = kt * 64;
        const int cur = kt & 1;
        const bool have_next = (kt + 1) < NT_;

        short8 nv0, nv1;
        if (have_next) {
            const unsigned short* vs = vrow + (size_t)(k0 + 64) * D_;
            nv0 = *(const short8*)vs;
            nv1 = *(const short8*)(vs + 8);
        }

        // ---- S^T = K Q^T ----
        f32x4 sacc[4];
        #pragma unroll
        for (int n = 0; n < 4; ++n) sacc[n] = f32x4{0.f, 0.f, 0.f, 0.f};
        #pragma unroll
        for (int n = 0; n < 4; ++n) {
            const unsigned short* kp = Kb + ((size_t)b * S_ + k0 + n * 16 + c) * D_ + h * DK_;
            short8 kf0 = *(const short8*)(kp + g * 8);
            short8 kf1 = *(const short8*)(kp + 32 + g * 8);
            sacc[n] = __builtin_amdgcn_mfma_f32_16x16x32_bf16(kf0, qf0, sacc[n], 0, 0, 0);
            sacc[n] = __builtin_amdgcn_mfma_f32_16x16x32_bf16(kf1, qf1, sacc[n], 0, 0, 0);
        }

        // ---- factor/mask + scores (nontemporal float4) + tile max ----
        const unsigned int w0 = brow[(k0 >> 5)];
        const unsigned int w1 = brow[(k0 >> 5) + 1];
        float pmax = -INFINITY;
        f32x4 sv[4];
        #pragma unroll
        for (int n = 0; n < 4; ++n) {
            const f32x4 fv = *(const f32x4*)&fac_lds[k0 + n * 16 + g * 4];
            const unsigned int wsel = (n < 2) ? w0 : w1;
            #pragma unroll
            for (int r = 0; r < 4; ++r) {
                const int kl = n * 16 + g * 4 + r;
                const float f = fv[r];
                const float icnt = fmaxf(f, 0.f);
                const float bit = (float)((wsel >> (kl & 31)) & 1u);
                float s = sacc[n][r] * 0.125f * (1.f + bit * icnt);
                s = (f < 0.f) ? -1e9f : s;
                sv[n][r] = s;
                pmax = fmaxf(pmax, s);
            }
            __builtin_nontemporal_store(sv[n], (f32x4*)&srow[k0 + n * 16 + g * 4]);
        }

        // ---- online softmax (per-lane scalar state) ----
        pmax = fmaxf(pmax, __shfl_xor(pmax, 16));
        pmax = fmaxf(pmax, __shfl_xor(pmax, 32));
        const float nm = fmaxf(mrow, pmax);
        const float scq = __expf(mrow - nm);
        mrow = nm;
        lrow *= scq;
        float sc_o[4];
        #pragma unroll
        for (int r = 0; r < 4; ++r) sc_o[r] = __shfl(scq, (lane & 48) | (g * 4 + r));
        #pragma unroll
        for (int n = 0; n < 4; ++n)
            #pragma unroll
            for (int r = 0; r < 4; ++r) o[n][r] *= sc_o[r];

        // ---- P = exp(S - m), vectorized transposed write ----
        #pragma unroll
        for (int n = 0; n < 4; ++n) {
            ushort4v pu;
            #pragma unroll
            for (int r = 0; r < 4; ++r) {
                const float p = __expf(sv[n][r] - mrow);
                lrow += p;
                pu[r] = bf16_rne(p);
            }
            *(ushort4v*)&P_lds[w][c][n * 16 + g * 4] = pu;
        }

        // ---- stage next V tile into other buffer ----
        if (have_next) {
            #pragma unroll
            for (int j = 0; j < 8; ++j) {
                VT_lds[cur ^ 1][half * 16 + j][kr]     = (unsigned short)nv0[j];
                VT_lds[cur ^ 1][half * 16 + 8 + j][kr] = (unsigned short)nv1[j];
            }
        }

        // ---- O += P V ----
        #pragma unroll
        for (int kk = 0; kk < 2; ++kk) {
            const short8 pa = *(const short8*)&P_lds[w][c][kk * 32 + g * 8];
            #pragma unroll
            for (int n = 0; n < 4; ++n) {
                const short8 vf = *(const short8*)&VT_lds[cur][n * 16 + c][kk * 32 + g * 8];
                o[n] = __builtin_amdgcn_mfma_f32_16x16x32_bf16(pa, vf, o[n], 0, 0, 0);
            }
        }
        __syncthreads();
    }

    // ---- finalize ----
    lrow += __shfl_xor(lrow, 16);
    lrow += __shfl_xor(lrow, 32);
    const float linv = 1.f / lrow;
    float linv_o[4];
    #pragma unroll
    for (int r = 0; r < 4; ++r) linv_o[r] = __shfl(linv, (lane & 48) | (g * 4 + r));
    #pragma unroll
    for (int n = 0; n < 4; ++n)
        #pragma unroll
        for (int r = 0; r < 4; ++r) {
            const size_t idx = ((size_t)b * S_ + qrow0 + g * 4 + r) * D_ + h * DK_ + n * 16 + c;
            X[idx] = bf16_rne(o[n][r] * linv_o[r]);
        }
}

extern "C" void kernel_launch(void* const* d_in, const int* in_sizes, int n_in,
                              void* d_out, int out_size, void* d_ws, size_t ws_size,
                              hipStream_t stream) {
    const float* query = (const float*)d_in[0];
    const float* key   = (const float*)d_in[1];
    const float* value = (const float*)d_in[2];
    const int*   mask  = (const int*)d_in[3];
    const float* mask1 = (const float*)d_in[4];
    const float* Wq = (const float*)d_in[5];
    const float* bq = (const float*)d_in[6];
    const float* Wk = (const float*)d_in[7];
    const float* bk = (const float*)d_in[8];
    const float* Wv = (const float*)d_in[9];
    const float* bv = (const float*)d_in[10];
    const float* Wo = (const float*)d_in[11];
    const float* bo = (const float*)d_in[12];

    float* ret_out    = (float*)d_out;               // f32 [B,S,D]
    float* scores_out = ret_out + RET_ELEMS;         // f32 [B,H,S,S]

    const size_t SZ = (size_t)B_ * S_ * D_;          // 3,145,728
    const size_t WZ = (size_t)D_ * D_;               // 1,048,576
    // ws layout (~53 MB): colsum | bits | Qb Kb Vb Xb | qf kf vf | Wqb Wkb Wvb Wob
    float* colsum = (float*)d_ws;
    unsigned int* bits = (unsigned int*)((char*)d_ws + 16384);
    unsigned short* Qb  = (unsigned short*)((char*)d_ws + 16384 + 589824);
    unsigned short* Kb  = Qb + SZ;
    unsigned short* Vb  = Kb + SZ;
    unsigned short* Xb  = Vb + SZ;
    unsigned short* qf  = Xb + SZ;
    unsigned short* kf  = qf + SZ;
    unsigned short* vf  = kf + SZ;
    unsigned short* Wqb = vf + SZ;
    unsigned short* Wkb = Wqb + WZ;
    unsigned short* Wvb = Wkb + WZ;
    unsigned short* Wob = Wvb + WZ;

    CvtJobs jobs;
    jobs.src[0] = query; jobs.dst[0] = qf;  jobs.n8[0] = (int)(SZ / 8);
    jobs.src[1] = key;   jobs.dst[1] = kf;  jobs.n8[1] = (int)(SZ / 8);
    jobs.src[2] = value; jobs.dst[2] = vf;  jobs.n8[2] = (int)(SZ / 8);
    jobs.src[3] = Wq;    jobs.dst[3] = Wqb; jobs.n8[3] = (int)(WZ / 8);
    jobs.src[4] = Wk;    jobs.dst[4] = Wkb; jobs.n8[4] = (int)(WZ / 8);
    jobs.src[5] = Wv;    jobs.dst[5] = Wvb; jobs.n8[5] = (int)(WZ / 8);
    jobs.src[6] = Wo;    jobs.dst[6] = Wob; jobs.n8[6] = (int)(WZ / 8);
    cvt_kernel<<<dim3((int)(SZ / 8 / 256), 7), 256, 0, stream>>>(jobs);

    bitpack_kernel<<<(B_ * S_ * S_) / 256, 256, 0, stream>>>(mask1, bits);
    colcount_bits_kernel<<<16, 256, 0, stream>>>(bits, colsum);

    Proj p0{qf, Wqb, bq, Qb}, p1{kf, Wkb, bk, Kb}, p2{vf, Wvb, bv, Vb};
    qkv_gemm_kernel<<<dim3(D_ / 128, (B_ * S_) / 128, 3), 512, 0, stream>>>(p0, p1, p2);

    attn_kernel<<<dim3(S_ / 64, H_, B_), 256, 0, stream>>>(Qb, Kb, Vb, mask, bits, colsum, scores_out, Xb);

    out_gemm_kernel<<<dim3(D_ / 64, (B_ * S_) / 64), 256, 0, stream>>>(Xb, Wob, bo, ret_out);
}

// Round 9
// 232.319 us; speedup vs baseline: 1.5431x; 1.0116x over previous
//
#include <hip/hip_runtime.h>
#include <hip/hip_bf16.h>

#define B_ 2
#define S_ 1536
#define D_ 1024
#define H_ 16
#define DK_ 64
#define KW_ 48                 // S_/32 mask-bit words per row
#define NT_ 24                 // S_/64 key tiles

#define RET_ELEMS 3145728      // f32 elems: [B,S,D]

typedef __attribute__((ext_vector_type(8))) short short8;
typedef __attribute__((ext_vector_type(8))) unsigned short ushort8v;
typedef __attribute__((ext_vector_type(4))) unsigned short ushort4v;
typedef __attribute__((ext_vector_type(4))) float f32x4;

__device__ __forceinline__ unsigned short bf16_rne(float f) {
    return __builtin_bit_cast(unsigned short, __float2bfloat16(f));
}

// ---------------- f32 -> bf16 bulk convert (7 arrays in one launch) ----------------
struct CvtJobs {
    const float* src[7];
    unsigned short* dst[7];
    int n8[7];                 // elements/8
};

__global__ __launch_bounds__(256) void cvt_kernel(CvtJobs j) {
    const int y = blockIdx.y;
    const int i = blockIdx.x * 256 + threadIdx.x;
    if (i >= j.n8[y]) return;
    const float* s = j.src[y] + (size_t)i * 8;
    float4 f0 = *(const float4*)s;
    float4 f1 = *(const float4*)(s + 4);
    ushort8v u;
    u[0]=bf16_rne(f0.x); u[1]=bf16_rne(f0.y); u[2]=bf16_rne(f0.z); u[3]=bf16_rne(f0.w);
    u[4]=bf16_rne(f1.x); u[5]=bf16_rne(f1.y); u[6]=bf16_rne(f1.z); u[7]=bf16_rne(f1.w);
    *(ushort8v*)(j.dst[y] + (size_t)i * 8) = u;
}

// ---------------- pack mask1 into bits + zero colsum ----------------
__global__ void bitpack_kernel(const float* __restrict__ mask1, unsigned int* __restrict__ bits,
                               float* __restrict__ colsum) {
    if (blockIdx.x < 12) colsum[blockIdx.x * 256 + threadIdx.x] = 0.f;
    const size_t gid = (size_t)blockIdx.x * 256 + threadIdx.x;   // over B*S*S
    const float v = mask1[gid];
    const unsigned long long bal = __ballot(v != 0.f);
    const int l = threadIdx.x & 63;
    if (l == 0)       bits[gid >> 5] = (unsigned int)bal;
    else if (l == 32) bits[gid >> 5] = (unsigned int)(bal >> 32);
}

// ---------------- column count from bits: 192 blocks, 96-row partials ----------------
__global__ void colcount_bits_kernel(const unsigned int* __restrict__ bits, float* __restrict__ colsum) {
    const int b     = blockIdx.x / 6;                 // grid.x = 12
    const int chunk = blockIdx.x % 6;
    const int col   = chunk * 256 + threadIdx.x;      // 0..1535
    const int q0    = blockIdx.y * 96;                // grid.y = 16
    const int wword = col >> 5, bit = col & 31;
    const unsigned int* p = bits + ((size_t)b * S_ + q0) * KW_ + wword;
    int s = 0;
    #pragma unroll 8
    for (int q = 0; q < 96; ++q) s += (p[(size_t)q * KW_] >> bit) & 1u;
    atomicAdd(&colsum[b * S_ + col], (float)s);       // integer-valued: exact
}

// ---------------- fused QKV projection GEMM: bf16 in, 128x128 tile, BK=64, 512 threads ----------------
// flat grid 576, XCD-swizzled: xcd=bid&7 owns 9 (z,y) A-panels; panel's 8 N-tiles stay on-XCD
struct Proj { const unsigned short* A; const unsigned short* W; const float* bias; unsigned short* C; };

__global__ __launch_bounds__(512) void qkv_gemm_kernel(Proj p0, Proj p1, Proj p2) {
    const int bid = blockIdx.x;
    const int xcd = bid & 7, idx = bid >> 3;          // idx 0..71
    const int zy = xcd * 9 + (idx >> 3);              // 0..71
    const int bx = idx & 7;
    const int z = zy / 24, by = zy % 24;

    const unsigned short* A = z == 0 ? p0.A    : (z == 1 ? p1.A    : p2.A);
    const unsigned short* W = z == 0 ? p0.W    : (z == 1 ? p1.W    : p2.W);
    const float* bias       = z == 0 ? p0.bias : (z == 1 ? p1.bias : p2.bias);
    unsigned short* C       = z == 0 ? p0.C    : (z == 1 ? p1.C    : p2.C);

    __shared__ unsigned short As[128][72];
    __shared__ unsigned short Bs[128][72];
    const int tid = threadIdx.x;
    const int w = tid >> 6, lane = tid & 63;
    const int g = lane >> 4, c = lane & 15;
    const int wm = w >> 2, wn = w & 3;        // 2x4 waves, wave tile 64x32
    const int m0 = by * 128, n0 = bx * 128;
    const int trow = tid >> 2;                // 0..127
    const int tcol = (tid & 3) * 16;          // 0,16,32,48

    f32x4 acc[4][2];
    #pragma unroll
    for (int m = 0; m < 4; ++m)
        #pragma unroll
        for (int n = 0; n < 2; ++n)
            acc[m][n] = f32x4{0.f, 0.f, 0.f, 0.f};

    for (int k0 = 0; k0 < D_; k0 += 64) {
        {
            const unsigned short* ap = A + (size_t)(m0 + trow) * D_ + k0 + tcol;
            *(ushort8v*)&As[trow][tcol]     = *(const ushort8v*)ap;
            *(ushort8v*)&As[trow][tcol + 8] = *(const ushort8v*)(ap + 8);
            const unsigned short* wp = W + (size_t)(n0 + trow) * D_ + k0 + tcol;
            *(ushort8v*)&Bs[trow][tcol]     = *(const ushort8v*)wp;
            *(ushort8v*)&Bs[trow][tcol + 8] = *(const ushort8v*)(wp + 8);
        }
        __syncthreads();
        #pragma unroll
        for (int kk = 0; kk < 2; ++kk) {
            short8 a[4], bb[2];
            #pragma unroll
            for (int m = 0; m < 4; ++m) a[m]  = *(const short8*)&As[wm * 64 + m * 16 + c][kk * 32 + g * 8];
            #pragma unroll
            for (int n = 0; n < 2; ++n) bb[n] = *(const short8*)&Bs[wn * 32 + n * 16 + c][kk * 32 + g * 8];
            __builtin_amdgcn_s_setprio(1);
            #pragma unroll
            for (int m = 0; m < 4; ++m)
                #pragma unroll
                for (int n = 0; n < 2; ++n)
                    acc[m][n] = __builtin_amdgcn_mfma_f32_16x16x32_bf16(a[m], bb[n], acc[m][n], 0, 0, 0);
            __builtin_amdgcn_s_setprio(0);
        }
        __syncthreads();
    }
    #pragma unroll
    for (int n = 0; n < 2; ++n) {
        const int col = n0 + wn * 32 + n * 16 + c;
        const float bval = bias[col];
        #pragma unroll
        for (int m = 0; m < 4; ++m) {
            const int row0 = m0 + wm * 64 + m * 16 + g * 4;
            #pragma unroll
            for (int r = 0; r < 4; ++r)
                C[(size_t)(row0 + r) * D_ + col] = bf16_rne(acc[m][n][r] + bval);
        }
    }
}

// ---------------- final projection: 64x64 tile, 256 threads, bf16 in, f32 out ----------------
// flat grid 768, XCD-swizzled
__global__ __launch_bounds__(256) void out_gemm_kernel(
    const unsigned short* __restrict__ A, const unsigned short* __restrict__ W,
    const float* __restrict__ bias, float* __restrict__ C)
{
    const int bid = blockIdx.x;
    const int xcd = bid & 7, idx = bid >> 3;          // idx 0..95
    const int yg = xcd * 6 + (idx >> 4);              // 0..47
    const int bx = idx & 15;                          // 0..15

    __shared__ unsigned short As[64][72];
    __shared__ unsigned short Bs[64][72];
    const int tid = threadIdx.x;
    const int w = tid >> 6, lane = tid & 63;
    const int g = lane >> 4, c = lane & 15;
    const int wm = w >> 1, wn = w & 1;        // 2x2 waves, wave tile 32x32
    const int m0 = yg * 64, n0 = bx * 64;
    const int trow = tid >> 2;                // 0..63
    const int tcol = (tid & 3) * 16;

    f32x4 acc[2][2];
    #pragma unroll
    for (int m = 0; m < 2; ++m)
        #pragma unroll
        for (int n = 0; n < 2; ++n)
            acc[m][n] = f32x4{0.f, 0.f, 0.f, 0.f};

    for (int k0 = 0; k0 < D_; k0 += 64) {
        {
            const unsigned short* ap = A + (size_t)(m0 + trow) * D_ + k0 + tcol;
            *(ushort8v*)&As[trow][tcol]     = *(const ushort8v*)ap;
            *(ushort8v*)&As[trow][tcol + 8] = *(const ushort8v*)(ap + 8);
            const unsigned short* wp = W + (size_t)(n0 + trow) * D_ + k0 + tcol;
            *(ushort8v*)&Bs[trow][tcol]     = *(const ushort8v*)wp;
            *(ushort8v*)&Bs[trow][tcol + 8] = *(const ushort8v*)(wp + 8);
        }
        __syncthreads();
        #pragma unroll
        for (int kk = 0; kk < 2; ++kk) {
            short8 a[2], bb[2];
            #pragma unroll
            for (int m = 0; m < 2; ++m) a[m]  = *(const short8*)&As[wm * 32 + m * 16 + c][kk * 32 + g * 8];
            #pragma unroll
            for (int n = 0; n < 2; ++n) bb[n] = *(const short8*)&Bs[wn * 32 + n * 16 + c][kk * 32 + g * 8];
            __builtin_amdgcn_s_setprio(1);
            #pragma unroll
            for (int m = 0; m < 2; ++m)
                #pragma unroll
                for (int n = 0; n < 2; ++n)
                    acc[m][n] = __builtin_amdgcn_mfma_f32_16x16x32_bf16(a[m], bb[n], acc[m][n], 0, 0, 0);
            __builtin_amdgcn_s_setprio(0);
        }
        __syncthreads();
    }
    #pragma unroll
    for (int n = 0; n < 2; ++n) {
        const int col = n0 + wn * 32 + n * 16 + c;
        const float bval = bias[col];
        #pragma unroll
        for (int m = 0; m < 2; ++m) {
            const int row0 = m0 + wm * 32 + m * 16 + g * 4;
            #pragma unroll
            for (int r = 0; r < 4; ++r)
                C[(size_t)(row0 + r) * D_ + col] = acc[m][n][r] + bval;
        }
    }
}

// ---------------- fused attention, S^T layout, 512 threads (QBLK=128), XCD-swizzled ----------------
__global__ __launch_bounds__(512) void attn_kernel(
    const unsigned short* __restrict__ Qb, const unsigned short* __restrict__ Kb,
    const unsigned short* __restrict__ Vb, const int* __restrict__ mask,
    const unsigned int* __restrict__ bits, const float* __restrict__ colsum,
    float* __restrict__ scores, unsigned short* __restrict__ X)
{
    // flat grid 384: xcd owns 4 (h,b) groups x 12 q-tiles -> K/V head slice stays in one L2
    const int bid = blockIdx.x;
    const int xcd = bid & 7, idx = bid >> 3;          // idx 0..47
    const int grp = xcd * 4 + idx / 12;               // 0..31
    const int qt  = idx % 12;
    const int h = grp & 15, b = grp >> 4;

    const int tid = threadIdx.x;
    const int w = tid >> 6, lane = tid & 63;
    const int g = lane >> 4, c = lane & 15;

    __shared__ unsigned short VT_lds[2][64][72];   // [buf][dk][k] transposed V tile
    __shared__ unsigned short P_lds[8][16][72];    // [wave][q][k] bf16 P
    __shared__ float fac_lds[S_];                  // per-key: masked ? -1 : 1/colcount

    for (int i = tid; i < S_; i += 512) {
        const int km = mask[b * S_ + i];
        const float cnt = colsum[b * S_ + i];
        fac_lds[i] = (km == 0) ? -1.f : ((cnt > 0.f) ? (1.f / cnt) : 0.f);
    }

    const int qrow0 = qt * 128 + w * 16;
    const unsigned short* qptr = Qb + ((size_t)b * S_ + qrow0 + c) * D_ + h * DK_;
    const short8 qf0 = *(const short8*)(qptr + g * 8);
    const short8 qf1 = *(const short8*)(qptr + 32 + g * 8);

    float mrow = -INFINITY, lrow = 0.f;   // per-lane state for q = qrow0 + c
    f32x4 o[4];
    #pragma unroll
    for (int n = 0; n < 4; ++n) o[n] = f32x4{0.f, 0.f, 0.f, 0.f};

    float* srow = scores + ((((size_t)(b * H_ + h)) * S_ + qrow0 + c) * S_);
    const unsigned int* brow = bits + ((size_t)b * S_ + qrow0 + c) * KW_;
    // V staging: 512 threads, each stages 8 dk values for one key column
    const int kr = tid & 63, half = tid >> 6;          // half 0..7 -> dk rows half*8..+8
    const unsigned short* vrow = Vb + ((size_t)b * S_ + kr) * D_ + h * DK_ + half * 8;

    {
        short8 v0 = *(const short8*)vrow;
        #pragma unroll
        for (int j = 0; j < 8; ++j)
            VT_lds[0][half * 8 + j][kr] = (unsigned short)v0[j];
    }
    __syncthreads();   // fac table + V tile 0 ready

    for (int kt = 0; kt < NT_; ++kt) {
        const int k0 = kt * 64;
        const int cur = kt & 1;
        const bool have_next = (kt + 1) < NT_;

        short8 nv0;
        if (have_next) nv0 = *(const short8*)(vrow + (size_t)(k0 + 64) * D_);

        // ---- S^T = K Q^T ----
        f32x4 sacc[4];
        #pragma unroll
        for (int n = 0; n < 4; ++n) sacc[n] = f32x4{0.f, 0.f, 0.f, 0.f};
        short8 kf0[4], kf1[4];
        #pragma unroll
        for (int n = 0; n < 4; ++n) {
            const unsigned short* kp = Kb + ((size_t)b * S_ + k0 + n * 16 + c) * D_ + h * DK_;
            kf0[n] = *(const short8*)(kp + g * 8);
            kf1[n] = *(const short8*)(kp + 32 + g * 8);
        }
        __builtin_amdgcn_s_setprio(1);
        #pragma unroll
        for (int n = 0; n < 4; ++n) {
            sacc[n] = __builtin_amdgcn_mfma_f32_16x16x32_bf16(kf0[n], qf0, sacc[n], 0, 0, 0);
            sacc[n] = __builtin_amdgcn_mfma_f32_16x16x32_bf16(kf1[n], qf1, sacc[n], 0, 0, 0);
        }
        __builtin_amdgcn_s_setprio(0);

        // ---- factor/mask + scores (nontemporal float4) + tile max ----
        const unsigned int w0 = brow[(k0 >> 5)];
        const unsigned int w1 = brow[(k0 >> 5) + 1];
        float pmax = -INFINITY;
        f32x4 sv[4];
        #pragma unroll
        for (int n = 0; n < 4; ++n) {
            const f32x4 fv = *(const f32x4*)&fac_lds[k0 + n * 16 + g * 4];
            const unsigned int wsel = (n < 2) ? w0 : w1;
            #pragma unroll
            for (int r = 0; r < 4; ++r) {
                const int kl = n * 16 + g * 4 + r;
                const float f = fv[r];
                const float icnt = fmaxf(f, 0.f);
                const float bit = (float)((wsel >> (kl & 31)) & 1u);
                float s = sacc[n][r] * 0.125f * (1.f + bit * icnt);
                s = (f < 0.f) ? -1e9f : s;
                sv[n][r] = s;
                pmax = fmaxf(pmax, s);
            }
            __builtin_nontemporal_store(sv[n], (f32x4*)&srow[k0 + n * 16 + g * 4]);
        }

        // ---- online softmax (per-lane scalar state) ----
        pmax = fmaxf(pmax, __shfl_xor(pmax, 16));
        pmax = fmaxf(pmax, __shfl_xor(pmax, 32));
        const float nm = fmaxf(mrow, pmax);
        const float scq = __expf(mrow - nm);
        mrow = nm;
        lrow *= scq;
        float sc_o[4];
        #pragma unroll
        for (int r = 0; r < 4; ++r) sc_o[r] = __shfl(scq, (lane & 48) | (g * 4 + r));
        #pragma unroll
        for (int n = 0; n < 4; ++n)
            #pragma unroll
            for (int r = 0; r < 4; ++r) o[n][r] *= sc_o[r];

        // ---- P = exp(S - m), vectorized transposed write ----
        #pragma unroll
        for (int n = 0; n < 4; ++n) {
            ushort4v pu;
            #pragma unroll
            for (int r = 0; r < 4; ++r) {
                const float p = __expf(sv[n][r] - mrow);
                lrow += p;
                pu[r] = bf16_rne(p);
            }
            *(ushort4v*)&P_lds[w][c][n * 16 + g * 4] = pu;
        }

        // ---- stage next V tile into other buffer ----
        if (have_next) {
            #pragma unroll
            for (int j = 0; j < 8; ++j)
                VT_lds[cur ^ 1][half * 8 + j][kr] = (unsigned short)nv0[j];
        }

        // ---- O += P V ----
        __builtin_amdgcn_s_setprio(1);
        #pragma unroll
        for (int kk = 0; kk < 2; ++kk) {
            const short8 pa = *(const short8*)&P_lds[w][c][kk * 32 + g * 8];
            #pragma unroll
            for (int n = 0; n < 4; ++n) {
                const short8 vf = *(const short8*)&VT_lds[cur][n * 16 + c][kk * 32 + g * 8];
                o[n] = __builtin_amdgcn_mfma_f32_16x16x32_bf16(pa, vf, o[n], 0, 0, 0);
            }
        }
        __builtin_amdgcn_s_setprio(0);
        __syncthreads();
    }

    // ---- finalize ----
    lrow += __shfl_xor(lrow, 16);
    lrow += __shfl_xor(lrow, 32);
    const float linv = 1.f / lrow;
    float linv_o[4];
    #pragma unroll
    for (int r = 0; r < 4; ++r) linv_o[r] = __shfl(linv, (lane & 48) | (g * 4 + r));
    #pragma unroll
    for (int n = 0; n < 4; ++n)
        #pragma unroll
        for (int r = 0; r < 4; ++r) {
            const size_t idx = ((size_t)b * S_ + qrow0 + g * 4 + r) * D_ + h * DK_ + n * 16 + c;
            X[idx] = bf16_rne(o[n][r] * linv_o[r]);
        }
}

extern "C" void kernel_launch(void* const* d_in, const int* in_sizes, int n_in,
                              void* d_out, int out_size, void* d_ws, size_t ws_size,
                              hipStream_t stream) {
    const float* query = (const float*)d_in[0];
    const float* key   = (const float*)d_in[1];
    const float* value = (const float*)d_in[2];
    const int*   mask  = (const int*)d_in[3];
    const float* mask1 = (const float*)d_in[4];
    const float* Wq = (const float*)d_in[5];
    const float* bq = (const float*)d_in[6];
    const float* Wk = (const float*)d_in[7];
    const float* bk = (const float*)d_in[8];
    const float* Wv = (const float*)d_in[9];
    const float* bv = (const float*)d_in[10];
    const float* Wo = (const float*)d_in[11];
    const float* bo = (const float*)d_in[12];

    float* ret_out    = (float*)d_out;               // f32 [B,S,D]
    float* scores_out = ret_out + RET_ELEMS;         // f32 [B,H,S,S]

    const size_t SZ = (size_t)B_ * S_ * D_;          // 3,145,728
    const size_t WZ = (size_t)D_ * D_;               // 1,048,576
    float* colsum = (float*)d_ws;
    unsigned int* bits = (unsigned int*)((char*)d_ws + 16384);
    unsigned short* Qb  = (unsigned short*)((char*)d_ws + 16384 + 589824);
    unsigned short* Kb  = Qb + SZ;
    unsigned short* Vb  = Kb + SZ;
    unsigned short* Xb  = Vb + SZ;
    unsigned short* qf  = Xb + SZ;
    unsigned short* kf  = qf + SZ;
    unsigned short* vf  = kf + SZ;
    unsigned short* Wqb = vf + SZ;
    unsigned short* Wkb = Wqb + WZ;
    unsigned short* Wvb = Wkb + WZ;
    unsigned short* Wob = Wvb + WZ;

    CvtJobs jobs;
    jobs.src[0] = query; jobs.dst[0] = qf;  jobs.n8[0] = (int)(SZ / 8);
    jobs.src[1] = key;   jobs.dst[1] = kf;  jobs.n8[1] = (int)(SZ / 8);
    jobs.src[2] = value; jobs.dst[2] = vf;  jobs.n8[2] = (int)(SZ / 8);
    jobs.src[3] = Wq;    jobs.dst[3] = Wqb; jobs.n8[3] = (int)(WZ / 8);
    jobs.src[4] = Wk;    jobs.dst[4] = Wkb; jobs.n8[4] = (int)(WZ / 8);
    jobs.src[5] = Wv;    jobs.dst[5] = Wvb; jobs.n8[5] = (int)(WZ / 8);
    jobs.src[6] = Wo;    jobs.dst[6] = Wob; jobs.n8[6] = (int)(WZ / 8);
    cvt_kernel<<<dim3((int)(SZ / 8 / 256), 7), 256, 0, stream>>>(jobs);

    bitpack_kernel<<<(B_ * S_ * S_) / 256, 256, 0, stream>>>(mask1, bits, colsum);
    colcount_bits_kernel<<<dim3(12, 16), 256, 0, stream>>>(bits, colsum);

    Proj p0{qf, Wqb, bq, Qb}, p1{kf, Wkb, bk, Kb}, p2{vf, Wvb, bv, Vb};
    qkv_gemm_kernel<<<576, 512, 0, stream>>>(p0, p1, p2);

    attn_kernel<<<384, 512, 0, stream>>>(Qb, Kb, Vb, mask, bits, colsum, scores_out, Xb);

    out_gemm_kernel<<<768, 256, 0, stream>>>(Xb, Wob, bo, ret_out);
}

// Round 10
// 201.576 us; speedup vs baseline: 1.7784x; 1.1525x over previous
//
#include <hip/hip_runtime.h>
#include <hip/hip_bf16.h>

#define B_ 2
#define S_ 1536
#define D_ 1024
#define H_ 16
#define DK_ 64
#define KW_ 48                 // S_/32 mask-bit words per row
#define NT_ 24                 // S_/64 key tiles

#define RET_ELEMS 3145728      // f32 elems: [B,S,D]
#define BITPACK_BLOCKS 18432   // B*S*S/256

typedef __attribute__((ext_vector_type(8))) short short8;
typedef __attribute__((ext_vector_type(8))) unsigned short ushort8v;
typedef __attribute__((ext_vector_type(4))) unsigned short ushort4v;
typedef __attribute__((ext_vector_type(4))) float f32x4;

__device__ __forceinline__ unsigned short bf16_rne(float f) {
    return __builtin_bit_cast(unsigned short, __float2bfloat16(f));
}

// ---------------- fused preproc: bitpack + colsum-zero + 7 f32->bf16 converts ----------------
struct CvtJobs {
    const float* src[7];
    unsigned short* dst[7];
};

__global__ __launch_bounds__(256) void preproc_kernel(
    const float* __restrict__ mask1, unsigned int* __restrict__ bits,
    float* __restrict__ colsum, CvtJobs j)
{
    const int blk = blockIdx.x;
    if (blk < BITPACK_BLOCKS) {
        if (blk < 12) colsum[blk * 256 + threadIdx.x] = 0.f;
        const size_t gid = (size_t)blk * 256 + threadIdx.x;
        const float v = mask1[gid];
        const unsigned long long bal = __ballot(v != 0.f);
        const int l = threadIdx.x & 63;
        if (l == 0)       bits[gid >> 5] = (unsigned int)bal;
        else if (l == 32) bits[gid >> 5] = (unsigned int)(bal >> 32);
        return;
    }
    int rb = blk - BITPACK_BLOCKS;     // 0..6655
    int job, base;
    if (rb < 4608) { job = rb / 1536; base = rb % 1536; }     // q,k,v: 1536 blocks each
    else { rb -= 4608; job = 3 + rb / 512; base = rb % 512; } // 4 weights: 512 each
    const size_t i = ((size_t)base * 256 + threadIdx.x) * 8;
    const float* s = j.src[job] + i;
    float4 f0 = *(const float4*)s;
    float4 f1 = *(const float4*)(s + 4);
    ushort8v u;
    u[0]=bf16_rne(f0.x); u[1]=bf16_rne(f0.y); u[2]=bf16_rne(f0.z); u[3]=bf16_rne(f0.w);
    u[4]=bf16_rne(f1.x); u[5]=bf16_rne(f1.y); u[6]=bf16_rne(f1.z); u[7]=bf16_rne(f1.w);
    *(ushort8v*)(j.dst[job] + i) = u;
}

// ---------------- column count from bits: 192 blocks, 96-row partials ----------------
__global__ void colcount_bits_kernel(const unsigned int* __restrict__ bits, float* __restrict__ colsum) {
    const int b     = blockIdx.x / 6;                 // grid.x = 12
    const int chunk = blockIdx.x % 6;
    const int col   = chunk * 256 + threadIdx.x;      // 0..1535
    const int q0    = blockIdx.y * 96;                // grid.y = 16
    const int wword = col >> 5, bit = col & 31;
    const unsigned int* p = bits + ((size_t)b * S_ + q0) * KW_ + wword;
    int s = 0;
    #pragma unroll 8
    for (int q = 0; q < 96; ++q) s += (p[(size_t)q * KW_] >> bit) & 1u;
    atomicAdd(&colsum[b * S_ + col], (float)s);       // integer-valued: exact
}

// ---------------- fused QKV projection GEMM: bf16 in, 128x128 tile, BK=64, 512 threads ----------------
struct Proj { const unsigned short* A; const unsigned short* W; const float* bias; unsigned short* C; };

__global__ __launch_bounds__(512) void qkv_gemm_kernel(Proj p0, Proj p1, Proj p2) {
    const int bid = blockIdx.x;
    const int xcd = bid & 7, idx = bid >> 3;          // idx 0..71
    const int zy = xcd * 9 + (idx >> 3);              // 0..71
    const int bx = idx & 7;
    const int z = zy / 24, by = zy % 24;

    const unsigned short* A = z == 0 ? p0.A    : (z == 1 ? p1.A    : p2.A);
    const unsigned short* W = z == 0 ? p0.W    : (z == 1 ? p1.W    : p2.W);
    const float* bias       = z == 0 ? p0.bias : (z == 1 ? p1.bias : p2.bias);
    unsigned short* C       = z == 0 ? p0.C    : (z == 1 ? p1.C    : p2.C);

    __shared__ unsigned short As[128][72];
    __shared__ unsigned short Bs[128][72];
    const int tid = threadIdx.x;
    const int w = tid >> 6, lane = tid & 63;
    const int g = lane >> 4, c = lane & 15;
    const int wm = w >> 2, wn = w & 3;        // 2x4 waves, wave tile 64x32
    const int m0 = by * 128, n0 = bx * 128;
    const int trow = tid >> 2;                // 0..127
    const int tcol = (tid & 3) * 16;          // 0,16,32,48

    f32x4 acc[4][2];
    #pragma unroll
    for (int m = 0; m < 4; ++m)
        #pragma unroll
        for (int n = 0; n < 2; ++n)
            acc[m][n] = f32x4{0.f, 0.f, 0.f, 0.f};

    for (int k0 = 0; k0 < D_; k0 += 64) {
        {
            const unsigned short* ap = A + (size_t)(m0 + trow) * D_ + k0 + tcol;
            *(ushort8v*)&As[trow][tcol]     = *(const ushort8v*)ap;
            *(ushort8v*)&As[trow][tcol + 8] = *(const ushort8v*)(ap + 8);
            const unsigned short* wp = W + (size_t)(n0 + trow) * D_ + k0 + tcol;
            *(ushort8v*)&Bs[trow][tcol]     = *(const ushort8v*)wp;
            *(ushort8v*)&Bs[trow][tcol + 8] = *(const ushort8v*)(wp + 8);
        }
        __syncthreads();
        #pragma unroll
        for (int kk = 0; kk < 2; ++kk) {
            short8 a[4], bb[2];
            #pragma unroll
            for (int m = 0; m < 4; ++m) a[m]  = *(const short8*)&As[wm * 64 + m * 16 + c][kk * 32 + g * 8];
            #pragma unroll
            for (int n = 0; n < 2; ++n) bb[n] = *(const short8*)&Bs[wn * 32 + n * 16 + c][kk * 32 + g * 8];
            __builtin_amdgcn_s_setprio(1);
            #pragma unroll
            for (int m = 0; m < 4; ++m)
                #pragma unroll
                for (int n = 0; n < 2; ++n)
                    acc[m][n] = __builtin_amdgcn_mfma_f32_16x16x32_bf16(a[m], bb[n], acc[m][n], 0, 0, 0);
            __builtin_amdgcn_s_setprio(0);
        }
        __syncthreads();
    }
    #pragma unroll
    for (int n = 0; n < 2; ++n) {
        const int col = n0 + wn * 32 + n * 16 + c;
        const float bval = bias[col];
        #pragma unroll
        for (int m = 0; m < 4; ++m) {
            const int row0 = m0 + wm * 64 + m * 16 + g * 4;
            #pragma unroll
            for (int r = 0; r < 4; ++r)
                C[(size_t)(row0 + r) * D_ + col] = bf16_rne(acc[m][n][r] + bval);
        }
    }
}

// ---------------- final projection: 64x64 tile, 256 threads, bf16 in, f32 out ----------------
__global__ __launch_bounds__(256) void out_gemm_kernel(
    const unsigned short* __restrict__ A, const unsigned short* __restrict__ W,
    const float* __restrict__ bias, float* __restrict__ C)
{
    const int bid = blockIdx.x;
    const int xcd = bid & 7, idx = bid >> 3;          // idx 0..95
    const int yg = xcd * 6 + (idx >> 4);              // 0..47
    const int bx = idx & 15;                          // 0..15

    __shared__ unsigned short As[64][72];
    __shared__ unsigned short Bs[64][72];
    const int tid = threadIdx.x;
    const int w = tid >> 6, lane = tid & 63;
    const int g = lane >> 4, c = lane & 15;
    const int wm = w >> 1, wn = w & 1;        // 2x2 waves, wave tile 32x32
    const int m0 = yg * 64, n0 = bx * 64;
    const int trow = tid >> 2;                // 0..63
    const int tcol = (tid & 3) * 16;

    f32x4 acc[2][2];
    #pragma unroll
    for (int m = 0; m < 2; ++m)
        #pragma unroll
        for (int n = 0; n < 2; ++n)
            acc[m][n] = f32x4{0.f, 0.f, 0.f, 0.f};

    for (int k0 = 0; k0 < D_; k0 += 64) {
        {
            const unsigned short* ap = A + (size_t)(m0 + trow) * D_ + k0 + tcol;
            *(ushort8v*)&As[trow][tcol]     = *(const ushort8v*)ap;
            *(ushort8v*)&As[trow][tcol + 8] = *(const ushort8v*)(ap + 8);
            const unsigned short* wp = W + (size_t)(n0 + trow) * D_ + k0 + tcol;
            *(ushort8v*)&Bs[trow][tcol]     = *(const ushort8v*)wp;
            *(ushort8v*)&Bs[trow][tcol + 8] = *(const ushort8v*)(wp + 8);
        }
        __syncthreads();
        #pragma unroll
        for (int kk = 0; kk < 2; ++kk) {
            short8 a[2], bb[2];
            #pragma unroll
            for (int m = 0; m < 2; ++m) a[m]  = *(const short8*)&As[wm * 32 + m * 16 + c][kk * 32 + g * 8];
            #pragma unroll
            for (int n = 0; n < 2; ++n) bb[n] = *(const short8*)&Bs[wn * 32 + n * 16 + c][kk * 32 + g * 8];
            __builtin_amdgcn_s_setprio(1);
            #pragma unroll
            for (int m = 0; m < 2; ++m)
                #pragma unroll
                for (int n = 0; n < 2; ++n)
                    acc[m][n] = __builtin_amdgcn_mfma_f32_16x16x32_bf16(a[m], bb[n], acc[m][n], 0, 0, 0);
            __builtin_amdgcn_s_setprio(0);
        }
        __syncthreads();
    }
    #pragma unroll
    for (int n = 0; n < 2; ++n) {
        const int col = n0 + wn * 32 + n * 16 + c;
        const float bval = bias[col];
        #pragma unroll
        for (int m = 0; m < 2; ++m) {
            const int row0 = m0 + wm * 32 + m * 16 + g * 4;
            #pragma unroll
            for (int r = 0; r < 4; ++r)
                C[(size_t)(row0 + r) * D_ + col] = acc[m][n][r] + bval;
        }
    }
}

// ---------------- fused attention, S^T layout, 256 threads (QBLK=64), grid 768 = 3 blocks/CU ----------------
__global__ __launch_bounds__(256) void attn_kernel(
    const unsigned short* __restrict__ Qb, const unsigned short* __restrict__ Kb,
    const unsigned short* __restrict__ Vb, const int* __restrict__ mask,
    const unsigned int* __restrict__ bits, const float* __restrict__ colsum,
    float* __restrict__ scores, unsigned short* __restrict__ X)
{
    // bijective XCD swizzle: 768 = 8 xcd x 96; each xcd owns 4 (b,h) groups x 24 q-tiles
    const int bid = blockIdx.x;
    const int xcd = bid & 7, idx = bid >> 3;          // idx 0..95
    const int grp = xcd * 4 + idx / 24;               // 0..31
    const int qt  = idx % 24;
    const int h = grp & 15, b = grp >> 4;

    const int tid = threadIdx.x;
    const int w = tid >> 6, lane = tid & 63;
    const int g = lane >> 4, c = lane & 15;

    __shared__ unsigned short VT_lds[2][64][72];   // [buf][dk][k] transposed V tile
    __shared__ unsigned short P_lds[4][16][72];    // [wave][q][k] bf16 P
    __shared__ float fac_lds[S_];                  // per-key: masked ? -1 : 1/colcount

    for (int i = tid; i < S_; i += 256) {
        const int km = mask[b * S_ + i];
        const float cnt = colsum[b * S_ + i];
        fac_lds[i] = (km == 0) ? -1.f : ((cnt > 0.f) ? (1.f / cnt) : 0.f);
    }

    const int qrow0 = qt * 64 + w * 16;
    const unsigned short* qptr = Qb + ((size_t)b * S_ + qrow0 + c) * D_ + h * DK_;
    const short8 qf0 = *(const short8*)(qptr + g * 8);
    const short8 qf1 = *(const short8*)(qptr + 32 + g * 8);

    float mrow = -INFINITY, lrow = 0.f;   // per-lane state for q = qrow0 + c
    f32x4 o[4];
    #pragma unroll
    for (int n = 0; n < 4; ++n) o[n] = f32x4{0.f, 0.f, 0.f, 0.f};

    float* srow = scores + ((((size_t)(b * H_ + h)) * S_ + qrow0 + c) * S_);
    const unsigned int* brow = bits + ((size_t)b * S_ + qrow0 + c) * KW_;
    const int kr = tid & 63, half = tid >> 6;
    const unsigned short* vrow = Vb + ((size_t)b * S_ + kr) * D_ + h * DK_ + half * 16;

    {
        short8 v0 = *(const short8*)vrow;
        short8 v1 = *(const short8*)(vrow + 8);
        #pragma unroll
        for (int j = 0; j < 8; ++j) {
            VT_lds[0][half * 16 + j][kr]     = (unsigned short)v0[j];
            VT_lds[0][half * 16 + 8 + j][kr] = (unsigned short)v1[j];
        }
    }
    __syncthreads();   // fac table + V tile 0 ready

    for (int kt = 0; kt < NT_; ++kt) {
        const int k0 = kt * 64;
        const int cur = kt & 1;
        const bool have_next = (kt + 1) < NT_;

        short8 nv0, nv1;
        if (have_next) {
            const unsigned short* vs = vrow + (size_t)(k0 + 64) * D_;
            nv0 = *(const short8*)vs;
            nv1 = *(const short8*)(vs + 8);
        }

        // ---- S^T = K Q^T ----
        f32x4 sacc[4];
        #pragma unroll
        for (int n = 0; n < 4; ++n) sacc[n] = f32x4{0.f, 0.f, 0.f, 0.f};
        short8 kf0[4], kf1[4];
        #pragma unroll
        for (int n = 0; n < 4; ++n) {
            const unsigned short* kp = Kb + ((size_t)b * S_ + k0 + n * 16 + c) * D_ + h * DK_;
            kf0[n] = *(const short8*)(kp + g * 8);
            kf1[n] = *(const short8*)(kp + 32 + g * 8);
        }
        __builtin_amdgcn_s_setprio(1);
        #pragma unroll
        for (int n = 0; n < 4; ++n) {
            sacc[n] = __builtin_amdgcn_mfma_f32_16x16x32_bf16(kf0[n], qf0, sacc[n], 0, 0, 0);
            sacc[n] = __builtin_amdgcn_mfma_f32_16x16x32_bf16(kf1[n], qf1, sacc[n], 0, 0, 0);
        }
        __builtin_amdgcn_s_setprio(0);

        // ---- factor/mask + scores (nontemporal float4) + tile max ----
        const unsigned int w0 = brow[(k0 >> 5)];
        const unsigned int w1 = brow[(k0 >> 5) + 1];
        float pmax = -INFINITY;
        f32x4 sv[4];
        #pragma unroll
        for (int n = 0; n < 4; ++n) {
            const f32x4 fv = *(const f32x4*)&fac_lds[k0 + n * 16 + g * 4];
            const unsigned int wsel = (n < 2) ? w0 : w1;
            #pragma unroll
            for (int r = 0; r < 4; ++r) {
                const int kl = n * 16 + g * 4 + r;
                const float f = fv[r];
                const float icnt = fmaxf(f, 0.f);
                const float bit = (float)((wsel >> (kl & 31)) & 1u);
                float s = sacc[n][r] * 0.125f * (1.f + bit * icnt);
                s = (f < 0.f) ? -1e9f : s;
                sv[n][r] = s;
                pmax = fmaxf(pmax, s);
            }
            __builtin_nontemporal_store(sv[n], (f32x4*)&srow[k0 + n * 16 + g * 4]);
        }

        // ---- online softmax (per-lane scalar state) ----
        pmax = fmaxf(pmax, __shfl_xor(pmax, 16));
        pmax = fmaxf(pmax, __shfl_xor(pmax, 32));
        const float nm = fmaxf(mrow, pmax);
        const float scq = __expf(mrow - nm);
        mrow = nm;
        lrow *= scq;
        float sc_o[4];
        #pragma unroll
        for (int r = 0; r < 4; ++r) sc_o[r] = __shfl(scq, (lane & 48) | (g * 4 + r));
        #pragma unroll
        for (int n = 0; n < 4; ++n)
            #pragma unroll
            for (int r = 0; r < 4; ++r) o[n][r] *= sc_o[r];

        // ---- P = exp(S - m), vectorized transposed write ----
        #pragma unroll
        for (int n = 0; n < 4; ++n) {
            ushort4v pu;
            #pragma unroll
            for (int r = 0; r < 4; ++r) {
                const float p = __expf(sv[n][r] - mrow);
                lrow += p;
                pu[r] = bf16_rne(p);
            }
            *(ushort4v*)&P_lds[w][c][n * 16 + g * 4] = pu;
        }

        // ---- stage next V tile into other buffer ----
        if (have_next) {
            #pragma unroll
            for (int j = 0; j < 8; ++j) {
                VT_lds[cur ^ 1][half * 16 + j][kr]     = (unsigned short)nv0[j];
                VT_lds[cur ^ 1][half * 16 + 8 + j][kr] = (unsigned short)nv1[j];
            }
        }

        // ---- O += P V ----
        __builtin_amdgcn_s_setprio(1);
        #pragma unroll
        for (int kk = 0; kk < 2; ++kk) {
            const short8 pa = *(const short8*)&P_lds[w][c][kk * 32 + g * 8];
            #pragma unroll
            for (int n = 0; n < 4; ++n) {
                const short8 vf = *(const short8*)&VT_lds[cur][n * 16 + c][kk * 32 + g * 8];
                o[n] = __builtin_amdgcn_mfma_f32_16x16x32_bf16(pa, vf, o[n], 0, 0, 0);
            }
        }
        __builtin_amdgcn_s_setprio(0);
        __syncthreads();
    }

    // ---- finalize ----
    lrow += __shfl_xor(lrow, 16);
    lrow += __shfl_xor(lrow, 32);
    const float linv = 1.f / lrow;
    float linv_o[4];
    #pragma unroll
    for (int r = 0; r < 4; ++r) linv_o[r] = __shfl(linv, (lane & 48) | (g * 4 + r));
    #pragma unroll
    for (int n = 0; n < 4; ++n)
        #pragma unroll
        for (int r = 0; r < 4; ++r) {
            const size_t idx = ((size_t)b * S_ + qrow0 + g * 4 + r) * D_ + h * DK_ + n * 16 + c;
            X[idx] = bf16_rne(o[n][r] * linv_o[r]);
        }
}

extern "C" void kernel_launch(void* const* d_in, const int* in_sizes, int n_in,
                              void* d_out, int out_size, void* d_ws, size_t ws_size,
                              hipStream_t stream) {
    const float* query = (const float*)d_in[0];
    const float* key   = (const float*)d_in[1];
    const float* value = (const float*)d_in[2];
    const int*   mask  = (const int*)d_in[3];
    const float* mask1 = (const float*)d_in[4];
    const float* Wq = (const float*)d_in[5];
    const float* bq = (const float*)d_in[6];
    const float* Wk = (const float*)d_in[7];
    const float* bk = (const float*)d_in[8];
    const float* Wv = (const float*)d_in[9];
    const float* bv = (const float*)d_in[10];
    const float* Wo = (const float*)d_in[11];
    const float* bo = (const float*)d_in[12];

    float* ret_out    = (float*)d_out;               // f32 [B,S,D]
    float* scores_out = ret_out + RET_ELEMS;         // f32 [B,H,S,S]

    const size_t SZ = (size_t)B_ * S_ * D_;          // 3,145,728
    const size_t WZ = (size_t)D_ * D_;               // 1,048,576
    float* colsum = (float*)d_ws;
    unsigned int* bits = (unsigned int*)((char*)d_ws + 16384);
    unsigned short* Qb  = (unsigned short*)((char*)d_ws + 16384 + 589824);
    unsigned short* Kb  = Qb + SZ;
    unsigned short* Vb  = Kb + SZ;
    unsigned short* Xb  = Vb + SZ;
    unsigned short* qf  = Xb + SZ;
    unsigned short* kf  = qf + SZ;
    unsigned short* vf  = kf + SZ;
    unsigned short* Wqb = vf + SZ;
    unsigned short* Wkb = Wqb + WZ;
    unsigned short* Wvb = Wkb + WZ;
    unsigned short* Wob = Wvb + WZ;

    CvtJobs jobs;
    jobs.src[0] = query; jobs.dst[0] = qf;
    jobs.src[1] = key;   jobs.dst[1] = kf;
    jobs.src[2] = value; jobs.dst[2] = vf;
    jobs.src[3] = Wq;    jobs.dst[3] = Wqb;
    jobs.src[4] = Wk;    jobs.dst[4] = Wkb;
    jobs.src[5] = Wv;    jobs.dst[5] = Wvb;
    jobs.src[6] = Wo;    jobs.dst[6] = Wob;

    preproc_kernel<<<BITPACK_BLOCKS + 3 * 1536 + 4 * 512, 256, 0, stream>>>(mask1, bits, colsum, jobs);
    colcount_bits_kernel<<<dim3(12, 16), 256, 0, stream>>>(bits, colsum);

    Proj p0{qf, Wqb, bq, Qb}, p1{kf, Wkb, bk, Kb}, p2{vf, Wvb, bv, Vb};
    qkv_gemm_kernel<<<576, 512, 0, stream>>>(p0, p1, p2);

    attn_kernel<<<768, 256, 0, stream>>>(Qb, Kb, Vb, mask, bits, colsum, scores_out, Xb);

    out_gemm_kernel<<<768, 256, 0, stream>>>(Xb, Wob, bo, ret_out);
}